// Round 1
// baseline (770.355 us; speedup 1.0000x reference)
//
#include <hip/hip_runtime.h>

// GraphGRU on MI355X — round 7: identical resubmit of round-6 best (773.5 µs).
// Round-6 bench failed on infra (container failed twice, no counters); re-establishing
// baseline + rocprof breakdown before the next theory-driven edit.
//   Quarter-wave gathers: 4 edges per VMEM instr (16 lanes/row; dwordx4 for 256B x|h row,
//   dwordx2 for 128B q row), shfl_xor merge. CSR binned by (dst, role(src)) -> 3 role-uniform
//   segments per node, no per-edge role logic; cnt_r from offsets.
//   GEMM unchanged (streaming barrier-free MFMA, 4 row-blocks/wave, role-uniform 256-blocks).

typedef __bf16 bf16;
typedef __bf16 bf16x8 __attribute__((ext_vector_type(8)));
typedef float  f32x4  __attribute__((ext_vector_type(4)));
typedef float  f32x2  __attribute__((ext_vector_type(2)));
typedef unsigned char u8;

#define DH 128

__device__ __forceinline__ float sigmoidf_(float x) { return 1.0f / (1.0f + expf(-x)); }

// ---------------- CSR build ----------------
// cnt3 bins: dst*3 + role(src). Also role histogram of nodes (ballot-aggregated).
__global__ __launch_bounds__(256) void hist_kernel(const int* __restrict__ ei, const int* __restrict__ role,
                                                   int* __restrict__ cnt3, int* __restrict__ rolecnt,
                                                   int E, int N)
{
  int i = blockIdx.x * 256 + threadIdx.x;
  int lane = threadIdx.x & 63;
  int r = (i < N) ? role[i] : -1;
  #pragma unroll
  for (int rr = 0; rr < 3; ++rr) {
    unsigned long long mask = __ballot(r == rr);
    if (lane == 0 && mask) atomicAdd(&rolecnt[rr], __popcll(mask));
  }
  if (i < E + N) {
    int src, dst;
    if (i < E) { src = ei[i]; dst = ei[E + i]; } else { src = i - E; dst = i - E; }
    int rs = (i < E) ? role[src] : r;     // self part: role[i-E] == r when i-E == i (i>=E path recompute)
    if (i >= E) rs = role[i - E];
    atomicAdd(&cnt3[dst * 3 + rs], 1);
  }
}

// hierarchical scan over n bins
__global__ __launch_bounds__(1024) void scan1_kernel(const int* __restrict__ cnt, int* __restrict__ off,
                                                     int* __restrict__ bsum, int n)
{
  __shared__ int wsum[16];
  int t = threadIdx.x, lane = t & 63, w = t >> 6;
  int idx = blockIdx.x * 1024 + t;
  int v = (idx < n) ? cnt[idx] : 0;
  int s = v;
  #pragma unroll
  for (int d = 1; d < 64; d <<= 1) { int u = __shfl_up(s, d); if (lane >= d) s += u; }
  if (lane == 63) wsum[w] = s;
  __syncthreads();
  if (w == 0 && lane < 16) {
    int ws = wsum[lane];
    #pragma unroll
    for (int d = 1; d < 16; d <<= 1) { int u = __shfl_up(ws, d); if (lane >= d) ws += u; }
    wsum[lane] = ws;
  }
  __syncthreads();
  int inc = ((w > 0) ? wsum[w - 1] : 0) + s;
  if (idx < n) off[idx + 1] = inc;
  if (t == 1023) bsum[blockIdx.x] = inc;
}

__global__ void scan2_kernel(int* __restrict__ bsum, int nb, const int* __restrict__ rolecnt,
                             int* __restrict__ rolefill, int* __restrict__ roleinfo)
{
  int lane = threadIdx.x;
  int carry = 0;
  for (int base = 0; base < nb; base += 64) {
    int v = (base + lane < nb) ? bsum[base + lane] : 0;
    int s = v;
    #pragma unroll
    for (int d = 1; d < 64; d <<= 1) { int u = __shfl_up(s, d); if (lane >= d) s += u; }
    if (base + lane < nb) bsum[base + lane] = carry + s - v;
    carry += __shfl(s, 63);
  }
  if (lane == 0) {
    int c0 = rolecnt[0], c1 = rolecnt[1], c2 = rolecnt[2];
    int s1 = (c0 + 255) & ~255;
    int s2 = s1 + ((c1 + 255) & ~255);
    int mp = s2 + ((c2 + 255) & ~255);
    rolefill[0] = 0; rolefill[1] = s1; rolefill[2] = s2;
    roleinfo[0] = s1; roleinfo[1] = s2;
    roleinfo[2] = c0;      roleinfo[3] = s1 - c0;
    roleinfo[4] = s1 + c1; roleinfo[5] = s2 - s1 - c1;
    roleinfo[6] = s2 + c2; roleinfo[7] = mp - s2 - c2;
  }
}

__global__ __launch_bounds__(1024) void scan3_kernel(int* __restrict__ off, int* __restrict__ fill,
                                                     const int* __restrict__ bsum, int n)
{
  int idx = blockIdx.x * 1024 + threadIdx.x;
  if (idx == 0) { off[0] = 0; fill[0] = 0; }
  if (idx < n) {
    int v = off[idx + 1] + bsum[blockIdx.x];
    off[idx + 1] = v;
    if (idx + 1 < n) fill[idx + 1] = v;
  }
}

// ssrc stores spos[src]; bin role derived from spos vs s1/s2
__global__ __launch_bounds__(256) void scatter_kernel(const int* __restrict__ ei, const int* __restrict__ spos,
                                                      const int* __restrict__ roleinfo,
                                                      int* __restrict__ fill3, int* __restrict__ ssrc, int E, int N)
{
  int i = blockIdx.x * 256 + threadIdx.x;
  if (i >= E + N) return;
  int s1 = roleinfo[0], s2 = roleinfo[1];
  int src, dst;
  if (i < E) { src = ei[i]; dst = ei[E + i]; } else { src = i - E; dst = i - E; }
  int t = spos[src];
  int r = (t >= s2) ? 2 : (t >= s1) ? 1 : 0;
  int pz = atomicAdd(&fill3[dst * 3 + r], 1);
  ssrc[pz] = t;
}

__global__ __launch_bounds__(256) void permscatter_kernel(const int* __restrict__ role, int* __restrict__ rolefill,
                                                          int* __restrict__ spos, int N)
{
  int i = blockIdx.x * 256 + threadIdx.x;
  int lane = threadIdx.x & 63;
  int r = (i < N) ? role[i] : -1;
  #pragma unroll
  for (int rr = 0; rr < 3; ++rr) {
    unsigned long long mask = __ballot(r == rr);
    if (!mask) continue;
    int base = 0;
    if (lane == 0) base = atomicAdd(&rolefill[rr], __popcll(mask));
    base = __shfl(base, 0);
    if (r == rr) {
      int rank = (int)__popcll(mask & ((1ull << lane) - 1ull));
      spos[i] = base + rank;
    }
  }
}

__global__ __launch_bounds__(256) void zeropad_kernel(const int* __restrict__ roleinfo,
                                                      bf16* __restrict__ Ax, bf16* __restrict__ Ah)
{
  int id = blockIdx.x * 256 + threadIdx.x;   // 98304
  int a = id / 49152, rem = id % 49152;
  int gp = rem / 16384, r2 = rem % 16384;
  int rr = r2 >> 6, c = r2 & 63;
  int gs = roleinfo[2 + gp * 2], gl = roleinfo[3 + gp * 2];
  if (rr < gl) {
    int row = gs + rr;
    size_t unit = (size_t)(row >> 4) * 1024 + c * 16 + (row & 15);
    bf16x8 z = {};
    ((bf16x8*)(a == 0 ? Ax : Ah))[unit] = z;
  }
}

// ---------------- prep ----------------
__global__ __launch_bounds__(256) void prep_xh_kernel(const float* __restrict__ x, const float* __restrict__ h,
                                                      const int* __restrict__ spos, u8* __restrict__ xq8,
                                                      bf16* __restrict__ Ax, bf16* __restrict__ Ah, int N)
{
  int g = blockIdx.x * 256 + threadIdx.x;
  if (g >= N * 32) return;
  int n = g >> 5, j = g & 31;
  int t = spos[n];
  const float* src = (j < 16) ? (x + (size_t)n * 128 + (j << 3))
                              : (h + (size_t)n * 128 + ((j - 16) << 3));
  float4 v0 = ((const float4*)src)[0];
  float4 v1 = ((const float4*)src)[1];
  int lo = __builtin_amdgcn_cvt_pk_fp8_f32(v0.x, v0.y, 0, false);
  lo = __builtin_amdgcn_cvt_pk_fp8_f32(v0.z, v0.w, lo, true);
  int hi = __builtin_amdgcn_cvt_pk_fp8_f32(v1.x, v1.y, 0, false);
  hi = __builtin_amdgcn_cvt_pk_fp8_f32(v1.z, v1.w, hi, true);
  *(int2*)(xq8 + (size_t)t * 256 + j * 8) = make_int2(lo, hi);
  bf16x8 o;
  o[0] = (bf16)v0.x; o[1] = (bf16)v0.y; o[2] = (bf16)v0.z; o[3] = (bf16)v0.w;
  o[4] = (bf16)v1.x; o[5] = (bf16)v1.y; o[6] = (bf16)v1.z; o[7] = (bf16)v1.w;
  size_t unit = (size_t)(t >> 4) * 1024 + (48 + (j & 15)) * 16 + (t & 15);
  ((bf16x8*)(j < 16 ? Ax : Ah))[unit] = o;
}

struct PrepW { const float* W[6]; const float* Wg[6]; const float* bg[6]; };
__global__ __launch_bounds__(256) void prep_wf_kernel(PrepW pw, bf16* __restrict__ Wf)
{
  int idx = blockIdx.x * 256 + threadIdx.x;
  if (idx >= 294912) return;
  int cv = idx / 49152, pos = idx % 49152;
  int ks4q = pos >> 10;
  int col = (pos >> 3) & 127, j = pos & 7;
  int k = (ks4q >> 2) * 32 + (ks4q & 3) * 8 + j;
  int r = k >> 7, kk = k & 127;
  float g = sigmoidf_(pw.Wg[cv][r * 128 + col] + pw.bg[cv][r * 128 + col]);
  Wf[idx] = (bf16)(pw.W[cv][kk * 128 + col] * g);
}

struct PrepP { const float* W[6]; const float* S[6]; };
__global__ __launch_bounds__(128) void prep_pf_kernel(PrepP pp, bf16* __restrict__ Pf)
{
  int b = blockIdx.x;                          // 6*3*128
  int cv = b / 384, rem = b % 384;
  int r = rem >> 7, kp = rem & 127;
  int col = threadIdx.x;
  const float* W = pp.W[cv] + (size_t)kp * 128;
  const float* S = pp.S[cv] + (size_t)r * 16384;
  float sum = 0.f;
  #pragma unroll 4
  for (int j2 = 0; j2 < 128; ++j2) sum += W[j2] * S[j2 * 128 + col];
  size_t o = (size_t)(cv * 3 + r) * 16384 + ((size_t)(kp >> 3) * 128 + col) * 8 + (kp & 7);
  Pf[o] = (bf16)sum;
}

// ---------------- gathers (quarter-wave: 4 edges per VMEM instr) ----------------
__global__ __launch_bounds__(256) void gather_xh_kernel(
    const u8* __restrict__ xq8, const int* __restrict__ off3, const int* __restrict__ ssrc,
    const int* __restrict__ spos, bf16* __restrict__ Ax, bf16* __restrict__ Ah,
    float4* __restrict__ cntf, int N)
{
  __shared__ alignas(16) bf16 lds[4][768];
  int w = threadIdx.x >> 6, lane = threadIdx.x & 63;
  int node = blockIdx.x * 4 + w;
  if (node >= N) return;
  int qt = lane >> 4, ql = lane & 15;
  int o0 = __builtin_amdgcn_readfirstlane(off3[node * 3]);
  int o1 = __builtin_amdgcn_readfirstlane(off3[node * 3 + 1]);
  int o2 = __builtin_amdgcn_readfirstlane(off3[node * 3 + 2]);
  int o3 = __builtin_amdgcn_readfirstlane(off3[node * 3 + 3]);
  float inv = 1.0f / (float)(o3 - o0);
  const u8* base = xq8 + ql * 16;
  int segs[4] = {o0, o1, o2, o3};

  #pragma unroll
  for (int rr = 0; rr < 3; ++rr) {
    int s = segs[rr], e = segs[rr + 1];
    float u[16];
    #pragma unroll
    for (int k = 0; k < 16; ++k) u[k] = 0.f;

    auto accum = [&](int4 d) {
      f32x2 f;
      f = __builtin_amdgcn_cvt_pk_f32_fp8(d.x, false); u[0] += f[0];  u[1] += f[1];
      f = __builtin_amdgcn_cvt_pk_f32_fp8(d.x, true);  u[2] += f[0];  u[3] += f[1];
      f = __builtin_amdgcn_cvt_pk_f32_fp8(d.y, false); u[4] += f[0];  u[5] += f[1];
      f = __builtin_amdgcn_cvt_pk_f32_fp8(d.y, true);  u[6] += f[0];  u[7] += f[1];
      f = __builtin_amdgcn_cvt_pk_f32_fp8(d.z, false); u[8] += f[0];  u[9] += f[1];
      f = __builtin_amdgcn_cvt_pk_f32_fp8(d.z, true);  u[10] += f[0]; u[11] += f[1];
      f = __builtin_amdgcn_cvt_pk_f32_fp8(d.w, false); u[12] += f[0]; u[13] += f[1];
      f = __builtin_amdgcn_cvt_pk_f32_fp8(d.w, true);  u[14] += f[0]; u[15] += f[1];
    };

    int i = s;
    for (; i + 16 <= e; i += 16) {
      int t0 = ssrc[i + qt];
      int t1 = ssrc[i + 4 + qt];
      int t2 = ssrc[i + 8 + qt];
      int t3 = ssrc[i + 12 + qt];
      int4 d0 = *(const int4*)(base + (size_t)t0 * 256);
      int4 d1 = *(const int4*)(base + (size_t)t1 * 256);
      int4 d2 = *(const int4*)(base + (size_t)t2 * 256);
      int4 d3 = *(const int4*)(base + (size_t)t3 * 256);
      accum(d0); accum(d1); accum(d2); accum(d3);
    }
    for (; i + 4 <= e; i += 4) {
      int t = ssrc[i + qt];
      int4 d = *(const int4*)(base + (size_t)t * 256);
      accum(d);
    }
    if (qt < e - i) {
      int t = ssrc[i + qt];
      int4 d = *(const int4*)(base + (size_t)t * 256);
      accum(d);
    }

    #pragma unroll
    for (int k = 0; k < 16; ++k) {
      u[k] += __shfl_xor(u[k], 16);
      u[k] += __shfl_xor(u[k], 32);
    }
    if (qt == 0) {
      int secbase = (ql < 8) ? (rr * 128 + ql * 16) : (384 + rr * 128 + (ql - 8) * 16);
      bf16x8 p0, p1;
      #pragma unroll
      for (int k = 0; k < 8; ++k) { p0[k] = (bf16)(u[k] * inv); p1[k] = (bf16)(u[8 + k] * inv); }
      *(bf16x8*)&lds[w][secbase] = p0;
      *(bf16x8*)&lds[w][secbase + 8] = p1;
    }
  }

  int t = spos[node];
  if (lane < 48) {
    size_t unit = (size_t)(t >> 4) * 1024 + lane * 16 + (t & 15);
    ((bf16x8*)Ax)[unit] = *(const bf16x8*)&lds[w][lane * 8];
    ((bf16x8*)Ah)[unit] = *(const bf16x8*)&lds[w][384 + lane * 8];
  }
  if (lane == 0)
    cntf[t] = make_float4((o1 - o0) * inv, (o2 - o1) * inv, (o3 - o2) * inv, (float)(o3 - o0));
}

__global__ __launch_bounds__(256) void gather_q_kernel(
    const u8* __restrict__ q8, const int* __restrict__ off3, const int* __restrict__ ssrc,
    const int* __restrict__ spos, bf16* __restrict__ Aq, int N)
{
  __shared__ alignas(16) bf16 lds[4][384];
  int w = threadIdx.x >> 6, lane = threadIdx.x & 63;
  int node = blockIdx.x * 4 + w;
  if (node >= N) return;
  int qt = lane >> 4, ql = lane & 15;
  int o0 = __builtin_amdgcn_readfirstlane(off3[node * 3]);
  int o1 = __builtin_amdgcn_readfirstlane(off3[node * 3 + 1]);
  int o2 = __builtin_amdgcn_readfirstlane(off3[node * 3 + 2]);
  int o3 = __builtin_amdgcn_readfirstlane(off3[node * 3 + 3]);
  float inv = 1.0f / (float)(o3 - o0);
  const u8* base = q8 + ql * 8;
  int segs[4] = {o0, o1, o2, o3};

  #pragma unroll
  for (int rr = 0; rr < 3; ++rr) {
    int s = segs[rr], e = segs[rr + 1];
    float u[8];
    #pragma unroll
    for (int k = 0; k < 8; ++k) u[k] = 0.f;

    auto accum = [&](int2 d) {
      f32x2 f;
      f = __builtin_amdgcn_cvt_pk_f32_fp8(d.x, false); u[0] += f[0]; u[1] += f[1];
      f = __builtin_amdgcn_cvt_pk_f32_fp8(d.x, true);  u[2] += f[0]; u[3] += f[1];
      f = __builtin_amdgcn_cvt_pk_f32_fp8(d.y, false); u[4] += f[0]; u[5] += f[1];
      f = __builtin_amdgcn_cvt_pk_f32_fp8(d.y, true);  u[6] += f[0]; u[7] += f[1];
    };

    int i = s;
    for (; i + 16 <= e; i += 16) {
      int t0 = ssrc[i + qt];
      int t1 = ssrc[i + 4 + qt];
      int t2 = ssrc[i + 8 + qt];
      int t3 = ssrc[i + 12 + qt];
      int2 d0 = *(const int2*)(base + (size_t)t0 * 128);
      int2 d1 = *(const int2*)(base + (size_t)t1 * 128);
      int2 d2 = *(const int2*)(base + (size_t)t2 * 128);
      int2 d3 = *(const int2*)(base + (size_t)t3 * 128);
      accum(d0); accum(d1); accum(d2); accum(d3);
    }
    for (; i + 4 <= e; i += 4) {
      int t = ssrc[i + qt];
      int2 d = *(const int2*)(base + (size_t)t * 128);
      accum(d);
    }
    if (qt < e - i) {
      int t = ssrc[i + qt];
      int2 d = *(const int2*)(base + (size_t)t * 128);
      accum(d);
    }

    #pragma unroll
    for (int k = 0; k < 8; ++k) {
      u[k] += __shfl_xor(u[k], 16);
      u[k] += __shfl_xor(u[k], 32);
    }
    if (qt == 0) {
      bf16x8 pk;
      #pragma unroll
      for (int k = 0; k < 8; ++k) pk[k] = (bf16)(u[k] * inv);
      *(bf16x8*)&lds[w][rr * 128 + ql * 8] = pk;
    }
  }

  int t = spos[node];
  if (lane < 48) {
    size_t unit = (size_t)(t >> 4) * 1024 + lane * 16 + (t & 15);
    ((bf16x8*)Aq)[unit] = *(const bf16x8*)&lds[w][lane * 8];
  }
}

// ---------------- streaming MFMA GEMM (no LDS/barriers; 4 row-blocks per wave) ----------------
struct GArgs {
  const bf16* Ap[5];
  const bf16* wf[5];
  const bf16* pf[5];
  bf16* out[5];
  const float* bias[5];
};

__global__ __launch_bounds__(256) void gemm_kernel(GArgs ga, const float4* __restrict__ cntf,
                                                   const int* __restrict__ roleinfo)
{
  const int cv = blockIdx.y;
  const bf16* __restrict__ Ap = ga.Ap[cv];
  const bf16* __restrict__ wf = ga.wf[cv];
  const bf16* __restrict__ pf = ga.pf[cv];
  bf16* __restrict__ out = ga.out[cv];
  const float* __restrict__ bias = ga.bias[cv];

  const int w = threadIdx.x >> 6, lane = threadIdx.x & 63;
  const int q = lane >> 4, l = lane & 15;
  const int rb0 = blockIdx.x * 16 + w * 4;
  const int row0 = blockIdx.x * 256;
  const int s1 = roleinfo[0], s2 = roleinfo[1];
  const int role = (row0 >= s2) ? 2 : (row0 >= s1) ? 1 : 0;
  const int laneoff = q * 128 + l;

  f32x4 acc[4][8];
  #pragma unroll
  for (int j = 0; j < 4; ++j)
    #pragma unroll
    for (int ct = 0; ct < 8; ++ct)
      #pragma unroll
      for (int k = 0; k < 4; ++k) acc[j][ct][k] = 0.f;

  const bf16x8* A0 = (const bf16x8*)Ap + (size_t)rb0 * 1024 + lane;
  const bf16x8* WF = (const bf16x8*)wf + laneoff;
  const bf16x8* PF = (const bf16x8*)pf + role * 2048 + laneoff;

  #pragma unroll 2
  for (int ks = 0; ks < 16; ++ks) {
    const bf16x8* bp = (ks < 12) ? (WF + ks * 512) : (PF + (ks - 12) * 512);
    bf16x8 a0 = A0[ks * 64];
    bf16x8 a1 = A0[1024 + ks * 64];
    bf16x8 a2 = A0[2048 + ks * 64];
    bf16x8 a3 = A0[3072 + ks * 64];
    #pragma unroll
    for (int ct = 0; ct < 8; ++ct) {
      bf16x8 b = bp[ct * 16];
      acc[0][ct] = __builtin_amdgcn_mfma_f32_16x16x32_bf16(a0, b, acc[0][ct], 0, 0, 0);
      acc[1][ct] = __builtin_amdgcn_mfma_f32_16x16x32_bf16(a1, b, acc[1][ct], 0, 0, 0);
      acc[2][ct] = __builtin_amdgcn_mfma_f32_16x16x32_bf16(a2, b, acc[2][ct], 0, 0, 0);
      acc[3][ct] = __builtin_amdgcn_mfma_f32_16x16x32_bf16(a3, b, acc[3][ct], 0, 0, 0);
    }
  }

  const bool hb = (bias != nullptr);
  #pragma unroll
  for (int j = 0; j < 4; ++j) {
    int rb = rb0 + j;
    float4 cfs[4];
    if (hb) {
      #pragma unroll
      for (int reg = 0; reg < 4; ++reg) cfs[reg] = cntf[rb * 16 + q * 4 + reg];
    }
    #pragma unroll
    for (int ct = 0; ct < 8; ++ct) {
      int col = ct * 16 + l;
      float b0 = 0, b1 = 0, b2 = 0;
      if (hb) { b0 = bias[col]; b1 = bias[128 + col]; b2 = bias[256 + col]; }
      #pragma unroll
      for (int reg = 0; reg < 4; ++reg) {
        int t = rb * 16 + q * 4 + reg;
        float v = acc[j][ct][reg];
        if (hb) v += cfs[reg].x * b0 + cfs[reg].y * b1 + cfs[reg].z * b2;
        out[(size_t)t * 128 + col] = (bf16)fmaxf(v, 0.f);
      }
    }
  }
}

// ---------------- combines ----------------
__global__ __launch_bounds__(256) void combine1_kernel(
    const bf16* __restrict__ o0, const bf16* __restrict__ o1,
    const bf16* __restrict__ o2, const bf16* __restrict__ o3,
    const float* __restrict__ h, const int* __restrict__ spos,
    float* __restrict__ zbuf, u8* __restrict__ q8, bf16* __restrict__ Aq, int N)
{
  int g = blockIdx.x * 256 + threadIdx.x;
  if (g >= N * 16) return;
  int n = g >> 4, o = g & 15;
  int t = spos[n];
  size_t tb = (size_t)t * 16 + o;
  bf16x8 a0 = ((const bf16x8*)o0)[tb];
  bf16x8 a1 = ((const bf16x8*)o1)[tb];
  bf16x8 a2 = ((const bf16x8*)o2)[tb];
  bf16x8 a3 = ((const bf16x8*)o3)[tb];
  size_t nb = (size_t)n * 16 + o;
  float4 h0 = ((const float4*)h)[nb * 2];
  float4 h1 = ((const float4*)h)[nb * 2 + 1];
  float hv[8] = {h0.x, h0.y, h0.z, h0.w, h1.x, h1.y, h1.z, h1.w};
  float zv[8], qv[8];
  bf16x8 qb;
  #pragma unroll
  for (int j = 0; j < 8; ++j) {
    zv[j] = sigmoidf_((float)a0[j] + (float)a1[j]);
    qv[j] = sigmoidf_((float)a2[j] + (float)a3[j]) * hv[j];
    qb[j] = (bf16)qv[j];
  }
  ((float4*)zbuf)[nb * 2]     = make_float4(zv[0], zv[1], zv[2], zv[3]);
  ((float4*)zbuf)[nb * 2 + 1] = make_float4(zv[4], zv[5], zv[6], zv[7]);
  int lo = __builtin_amdgcn_cvt_pk_fp8_f32(qv[0], qv[1], 0, false);
  lo = __builtin_amdgcn_cvt_pk_fp8_f32(qv[2], qv[3], lo, true);
  int hi = __builtin_amdgcn_cvt_pk_fp8_f32(qv[4], qv[5], 0, false);
  hi = __builtin_amdgcn_cvt_pk_fp8_f32(qv[6], qv[7], hi, true);
  *(int2*)(q8 + (size_t)t * 128 + o * 8) = make_int2(lo, hi);
  size_t unit = (size_t)(t >> 4) * 1024 + (48 + o) * 16 + (t & 15);
  ((bf16x8*)Aq)[unit] = qb;
}

__global__ __launch_bounds__(256) void combine2_kernel(
    const float* __restrict__ zbuf, const bf16* __restrict__ o4, const bf16* __restrict__ o5,
    const float* __restrict__ h, const int* __restrict__ spos, float* __restrict__ out, int N)
{
  int g = blockIdx.x * 256 + threadIdx.x;
  if (g >= N * 16) return;
  int n = g >> 4, o = g & 15;
  int t = spos[n];
  size_t tb = (size_t)t * 16 + o;
  bf16x8 a = ((const bf16x8*)o4)[tb];
  bf16x8 b = ((const bf16x8*)o5)[tb];
  size_t nb = (size_t)n * 16 + o;
  float4 z0 = ((const float4*)zbuf)[nb * 2];
  float4 z1 = ((const float4*)zbuf)[nb * 2 + 1];
  float4 h0 = ((const float4*)h)[nb * 2];
  float4 h1 = ((const float4*)h)[nb * 2 + 1];
  float zv[8] = {z0.x, z0.y, z0.z, z0.w, z1.x, z1.y, z1.z, z1.w};
  float hv[8] = {h0.x, h0.y, h0.z, h0.w, h1.x, h1.y, h1.z, h1.w};
  float ov[8];
  #pragma unroll
  for (int j = 0; j < 8; ++j)
    ov[j] = zv[j] * hv[j] + (1.f - zv[j]) * tanhf((float)a[j] + (float)b[j]);
  ((float4*)out)[nb * 2]     = make_float4(ov[0], ov[1], ov[2], ov[3]);
  ((float4*)out)[nb * 2 + 1] = make_float4(ov[4], ov[5], ov[6], ov[7]);
}

// ---------------- host ----------------
extern "C" void kernel_launch(void* const* d_in, const int* in_sizes, int n_in,
                              void* d_out, int out_size, void* d_ws, size_t ws_size,
                              hipStream_t stream)
{
  (void)n_in; (void)out_size; (void)ws_size;
  const float* x    = (const float*)d_in[0];
  const float* h    = (const float*)d_in[1];
  const int*   ei   = (const int*)d_in[2];
  const int*   role = (const int*)d_in[3];
  const int N = in_sizes[0] / DH;
  const int E = in_sizes[2] / 2;
  const int Etot = E + N;
  const int rows_pad = ((N + 765) + 255) & ~255;
  const int gx = rows_pad / 256;
  const int n3 = N * 3;
  const int nb3 = (n3 + 1023) / 1024;

  // conv order: 0 xz, 1 hz, 2 xr, 3 hr, 4 xh, 5 hh
  static const int Wi[6]  = {4, 9, 13, 18, 22, 27};
  static const int Wgi[6] = {5, 10, 14, 19, 23, 28};
  static const int bgi[6] = {6, 11, 15, 20, 24, 29};
  static const int Si[6]  = {7, 12, 16, 21, 25, 30};

  char* p = (char*)d_ws;
  auto alloc = [&](size_t bytes) -> char* {
    char* r = p;
    p += (bytes + 255) & ~(size_t)255;
    return r;
  };

  bf16* Ax = (bf16*)alloc((size_t)rows_pad * 512 * 2);   // Aq aliases Ax
  bf16* Ah = (bf16*)alloc((size_t)rows_pad * 512 * 2);
  bf16* Aq = Ax;
  u8* xq8  = (u8*)alloc((size_t)rows_pad * 256);
  u8* q8   = (u8*)alloc((size_t)rows_pad * 128);
  bf16* outs[6];
  for (int c = 0; c < 5; ++c) outs[c] = (bf16*)alloc((size_t)rows_pad * 128 * 2);
  outs[5] = outs[0];
  float* zbuf = (float*)alloc((size_t)N * 128 * 4);
  float4* cntf = (float4*)alloc((size_t)rows_pad * 16);
  bf16* Wf = (bf16*)alloc((size_t)6 * 49152 * 2);
  bf16* Pf = (bf16*)alloc((size_t)18 * 16384 * 2);
  int* cnt3  = (int*)alloc((size_t)n3 * 4);
  int* off3  = (int*)alloc((size_t)(n3 + 1) * 4);
  int* fill3 = (int*)alloc((size_t)n3 * 4);
  int* bsum  = (int*)alloc((size_t)(nb3 + 1) * 4);
  int* ssrc  = (int*)alloc((size_t)Etot * 4);
  int* spos  = (int*)alloc((size_t)N * 4);
  int* rolecnt  = (int*)alloc(64);
  int* rolefill = (int*)alloc(64);
  int* roleinfo = (int*)alloc(64);

  hipMemsetAsync(cnt3, 0, (size_t)n3 * 4, stream);
  hipMemsetAsync(rolecnt, 0, 16, stream);

  int egrid = (Etot + 255) / 256;
  int ngrid = (N + 255) / 256;
  hist_kernel<<<egrid, 256, 0, stream>>>(ei, role, cnt3, rolecnt, E, N);
  scan1_kernel<<<nb3, 1024, 0, stream>>>(cnt3, off3, bsum, n3);
  scan2_kernel<<<1, 64, 0, stream>>>(bsum, nb3, rolecnt, rolefill, roleinfo);
  scan3_kernel<<<nb3, 1024, 0, stream>>>(off3, fill3, bsum, n3);
  permscatter_kernel<<<ngrid, 256, 0, stream>>>(role, rolefill, spos, N);
  scatter_kernel<<<egrid, 256, 0, stream>>>(ei, spos, roleinfo, fill3, ssrc, E, N);
  zeropad_kernel<<<384, 256, 0, stream>>>(roleinfo, Ax, Ah);

  prep_xh_kernel<<<(N * 32 + 255) / 256, 256, 0, stream>>>(x, h, spos, xq8, Ax, Ah, N);

  PrepW pw;
  for (int c = 0; c < 6; ++c) {
    pw.W[c] = (const float*)d_in[Wi[c]];
    pw.Wg[c] = (const float*)d_in[Wgi[c]];
    pw.bg[c] = (const float*)d_in[bgi[c]];
  }
  prep_wf_kernel<<<1152, 256, 0, stream>>>(pw, Wf);
  PrepP pp;
  for (int c = 0; c < 6; ++c) { pp.W[c] = (const float*)d_in[Wi[c]]; pp.S[c] = (const float*)d_in[Si[c]]; }
  prep_pf_kernel<<<2304, 128, 0, stream>>>(pp, Pf);

  gather_xh_kernel<<<(N + 3) / 4, 256, 0, stream>>>(xq8, off3, ssrc, spos, Ax, Ah, cntf, N);

  // pass 1: one dispatch, cv 0..4 = {xz,xr,xh on Ax (bias)} + {hz,hr on Ah}
  GArgs g0;
  { int cvs[5] = {0, 2, 4, 1, 3};
    static const int bi2[5] = {8, 17, 26, -1, -1};
    const bf16* Apts[5] = {Ax, Ax, Ax, Ah, Ah};
    for (int k = 0; k < 5; ++k) {
      int c = cvs[k];
      g0.Ap[k] = Apts[k];
      g0.wf[k] = Wf + (size_t)c * 49152;
      g0.pf[k] = Pf + (size_t)c * 3 * 16384;
      g0.out[k] = outs[c];
      g0.bias[k] = (bi2[k] >= 0) ? (const float*)d_in[bi2[k]] : nullptr;
    } }
  gemm_kernel<<<dim3(gx, 5), 256, 0, stream>>>(g0, cntf, roleinfo);

  combine1_kernel<<<(N * 16 + 255) / 256, 256, 0, stream>>>(outs[0], outs[1], outs[2], outs[3],
                                                            h, spos, zbuf, q8, Aq, N);

  gather_q_kernel<<<(N + 3) / 4, 256, 0, stream>>>(q8, off3, ssrc, spos, Aq, N);

  // pass 2: conv hh(5) on Aq
  GArgs g2 = {};
  g2.Ap[0] = Aq;
  g2.wf[0] = Wf + (size_t)5 * 49152;
  g2.pf[0] = Pf + (size_t)5 * 3 * 16384;
  g2.out[0] = outs[5];
  g2.bias[0] = nullptr;
  gemm_kernel<<<dim3(gx, 1), 256, 0, stream>>>(g2, cntf, roleinfo);

  combine2_kernel<<<(N * 16 + 255) / 256, 256, 0, stream>>>(zbuf, outs[4], outs[5], h, spos,
                                                            (float*)d_out, N);
}

// Round 2
// 756.298 us; speedup vs baseline: 1.0186x; 1.0186x over previous
//
#include <hip/hip_runtime.h>

// GraphGRU on MI355X — round 8.
//   Gathers restructured: single flat loop over the node's full edge range [o0,o3)
//   (16-edge batches, 4 independent index->data chains in flight), per-quarter role
//   selection via exec-masked branch into static u0/u1/u2 accumulators. Removes the
//   short per-role segment loops (avg 11 edges) that serialized VMEM latency.
//   Everything else identical to round-7 baseline (770.4 µs).

typedef __bf16 bf16;
typedef __bf16 bf16x8 __attribute__((ext_vector_type(8)));
typedef float  f32x4  __attribute__((ext_vector_type(4)));
typedef float  f32x2  __attribute__((ext_vector_type(2)));
typedef unsigned char u8;

#define DH 128

__device__ __forceinline__ float sigmoidf_(float x) { return 1.0f / (1.0f + expf(-x)); }

// ---------------- CSR build ----------------
__global__ __launch_bounds__(256) void hist_kernel(const int* __restrict__ ei, const int* __restrict__ role,
                                                   int* __restrict__ cnt3, int* __restrict__ rolecnt,
                                                   int E, int N)
{
  int i = blockIdx.x * 256 + threadIdx.x;
  int lane = threadIdx.x & 63;
  int r = (i < N) ? role[i] : -1;
  #pragma unroll
  for (int rr = 0; rr < 3; ++rr) {
    unsigned long long mask = __ballot(r == rr);
    if (lane == 0 && mask) atomicAdd(&rolecnt[rr], __popcll(mask));
  }
  if (i < E + N) {
    int src, dst;
    if (i < E) { src = ei[i]; dst = ei[E + i]; } else { src = i - E; dst = i - E; }
    int rs = (i < E) ? role[src] : r;
    if (i >= E) rs = role[i - E];
    atomicAdd(&cnt3[dst * 3 + rs], 1);
  }
}

__global__ __launch_bounds__(1024) void scan1_kernel(const int* __restrict__ cnt, int* __restrict__ off,
                                                     int* __restrict__ bsum, int n)
{
  __shared__ int wsum[16];
  int t = threadIdx.x, lane = t & 63, w = t >> 6;
  int idx = blockIdx.x * 1024 + t;
  int v = (idx < n) ? cnt[idx] : 0;
  int s = v;
  #pragma unroll
  for (int d = 1; d < 64; d <<= 1) { int u = __shfl_up(s, d); if (lane >= d) s += u; }
  if (lane == 63) wsum[w] = s;
  __syncthreads();
  if (w == 0 && lane < 16) {
    int ws = wsum[lane];
    #pragma unroll
    for (int d = 1; d < 16; d <<= 1) { int u = __shfl_up(ws, d); if (lane >= d) ws += u; }
    wsum[lane] = ws;
  }
  __syncthreads();
  int inc = ((w > 0) ? wsum[w - 1] : 0) + s;
  if (idx < n) off[idx + 1] = inc;
  if (t == 1023) bsum[blockIdx.x] = inc;
}

__global__ void scan2_kernel(int* __restrict__ bsum, int nb, const int* __restrict__ rolecnt,
                             int* __restrict__ rolefill, int* __restrict__ roleinfo)
{
  int lane = threadIdx.x;
  int carry = 0;
  for (int base = 0; base < nb; base += 64) {
    int v = (base + lane < nb) ? bsum[base + lane] : 0;
    int s = v;
    #pragma unroll
    for (int d = 1; d < 64; d <<= 1) { int u = __shfl_up(s, d); if (lane >= d) s += u; }
    if (base + lane < nb) bsum[base + lane] = carry + s - v;
    carry += __shfl(s, 63);
  }
  if (lane == 0) {
    int c0 = rolecnt[0], c1 = rolecnt[1], c2 = rolecnt[2];
    int s1 = (c0 + 255) & ~255;
    int s2 = s1 + ((c1 + 255) & ~255);
    int mp = s2 + ((c2 + 255) & ~255);
    rolefill[0] = 0; rolefill[1] = s1; rolefill[2] = s2;
    roleinfo[0] = s1; roleinfo[1] = s2;
    roleinfo[2] = c0;      roleinfo[3] = s1 - c0;
    roleinfo[4] = s1 + c1; roleinfo[5] = s2 - s1 - c1;
    roleinfo[6] = s2 + c2; roleinfo[7] = mp - s2 - c2;
  }
}

__global__ __launch_bounds__(1024) void scan3_kernel(int* __restrict__ off, int* __restrict__ fill,
                                                     const int* __restrict__ bsum, int n)
{
  int idx = blockIdx.x * 1024 + threadIdx.x;
  if (idx == 0) { off[0] = 0; fill[0] = 0; }
  if (idx < n) {
    int v = off[idx + 1] + bsum[blockIdx.x];
    off[idx + 1] = v;
    if (idx + 1 < n) fill[idx + 1] = v;
  }
}

__global__ __launch_bounds__(256) void scatter_kernel(const int* __restrict__ ei, const int* __restrict__ spos,
                                                      const int* __restrict__ roleinfo,
                                                      int* __restrict__ fill3, int* __restrict__ ssrc, int E, int N)
{
  int i = blockIdx.x * 256 + threadIdx.x;
  if (i >= E + N) return;
  int s1 = roleinfo[0], s2 = roleinfo[1];
  int src, dst;
  if (i < E) { src = ei[i]; dst = ei[E + i]; } else { src = i - E; dst = i - E; }
  int t = spos[src];
  int r = (t >= s2) ? 2 : (t >= s1) ? 1 : 0;
  int pz = atomicAdd(&fill3[dst * 3 + r], 1);
  ssrc[pz] = t;
}

__global__ __launch_bounds__(256) void permscatter_kernel(const int* __restrict__ role, int* __restrict__ rolefill,
                                                          int* __restrict__ spos, int N)
{
  int i = blockIdx.x * 256 + threadIdx.x;
  int lane = threadIdx.x & 63;
  int r = (i < N) ? role[i] : -1;
  #pragma unroll
  for (int rr = 0; rr < 3; ++rr) {
    unsigned long long mask = __ballot(r == rr);
    if (!mask) continue;
    int base = 0;
    if (lane == 0) base = atomicAdd(&rolefill[rr], __popcll(mask));
    base = __shfl(base, 0);
    if (r == rr) {
      int rank = (int)__popcll(mask & ((1ull << lane) - 1ull));
      spos[i] = base + rank;
    }
  }
}

__global__ __launch_bounds__(256) void zeropad_kernel(const int* __restrict__ roleinfo,
                                                      bf16* __restrict__ Ax, bf16* __restrict__ Ah)
{
  int id = blockIdx.x * 256 + threadIdx.x;   // 98304
  int a = id / 49152, rem = id % 49152;
  int gp = rem / 16384, r2 = rem % 16384;
  int rr = r2 >> 6, c = r2 & 63;
  int gs = roleinfo[2 + gp * 2], gl = roleinfo[3 + gp * 2];
  if (rr < gl) {
    int row = gs + rr;
    size_t unit = (size_t)(row >> 4) * 1024 + c * 16 + (row & 15);
    bf16x8 z = {};
    ((bf16x8*)(a == 0 ? Ax : Ah))[unit] = z;
  }
}

// ---------------- prep ----------------
__global__ __launch_bounds__(256) void prep_xh_kernel(const float* __restrict__ x, const float* __restrict__ h,
                                                      const int* __restrict__ spos, u8* __restrict__ xq8,
                                                      bf16* __restrict__ Ax, bf16* __restrict__ Ah, int N)
{
  int g = blockIdx.x * 256 + threadIdx.x;
  if (g >= N * 32) return;
  int n = g >> 5, j = g & 31;
  int t = spos[n];
  const float* src = (j < 16) ? (x + (size_t)n * 128 + (j << 3))
                              : (h + (size_t)n * 128 + ((j - 16) << 3));
  float4 v0 = ((const float4*)src)[0];
  float4 v1 = ((const float4*)src)[1];
  int lo = __builtin_amdgcn_cvt_pk_fp8_f32(v0.x, v0.y, 0, false);
  lo = __builtin_amdgcn_cvt_pk_fp8_f32(v0.z, v0.w, lo, true);
  int hi = __builtin_amdgcn_cvt_pk_fp8_f32(v1.x, v1.y, 0, false);
  hi = __builtin_amdgcn_cvt_pk_fp8_f32(v1.z, v1.w, hi, true);
  *(int2*)(xq8 + (size_t)t * 256 + j * 8) = make_int2(lo, hi);
  bf16x8 o;
  o[0] = (bf16)v0.x; o[1] = (bf16)v0.y; o[2] = (bf16)v0.z; o[3] = (bf16)v0.w;
  o[4] = (bf16)v1.x; o[5] = (bf16)v1.y; o[6] = (bf16)v1.z; o[7] = (bf16)v1.w;
  size_t unit = (size_t)(t >> 4) * 1024 + (48 + (j & 15)) * 16 + (t & 15);
  ((bf16x8*)(j < 16 ? Ax : Ah))[unit] = o;
}

struct PrepW { const float* W[6]; const float* Wg[6]; const float* bg[6]; };
__global__ __launch_bounds__(256) void prep_wf_kernel(PrepW pw, bf16* __restrict__ Wf)
{
  int idx = blockIdx.x * 256 + threadIdx.x;
  if (idx >= 294912) return;
  int cv = idx / 49152, pos = idx % 49152;
  int ks4q = pos >> 10;
  int col = (pos >> 3) & 127, j = pos & 7;
  int k = (ks4q >> 2) * 32 + (ks4q & 3) * 8 + j;
  int r = k >> 7, kk = k & 127;
  float g = sigmoidf_(pw.Wg[cv][r * 128 + col] + pw.bg[cv][r * 128 + col]);
  Wf[idx] = (bf16)(pw.W[cv][kk * 128 + col] * g);
}

struct PrepP { const float* W[6]; const float* S[6]; };
__global__ __launch_bounds__(128) void prep_pf_kernel(PrepP pp, bf16* __restrict__ Pf)
{
  int b = blockIdx.x;                          // 6*3*128
  int cv = b / 384, rem = b % 384;
  int r = rem >> 7, kp = rem & 127;
  int col = threadIdx.x;
  const float* W = pp.W[cv] + (size_t)kp * 128;
  const float* S = pp.S[cv] + (size_t)r * 16384;
  float sum = 0.f;
  #pragma unroll 4
  for (int j2 = 0; j2 < 128; ++j2) sum += W[j2] * S[j2 * 128 + col];
  size_t o = (size_t)(cv * 3 + r) * 16384 + ((size_t)(kp >> 3) * 128 + col) * 8 + (kp & 7);
  Pf[o] = (bf16)sum;
}

// ---------------- gathers (flat-range, role by predication, 4 chains in flight) ----------------
#define ACCUM16(U, d) do { f32x2 f_;                                                   \
  f_ = __builtin_amdgcn_cvt_pk_f32_fp8((d).x, false); U[0]  += f_[0]; U[1]  += f_[1];  \
  f_ = __builtin_amdgcn_cvt_pk_f32_fp8((d).x, true);  U[2]  += f_[0]; U[3]  += f_[1];  \
  f_ = __builtin_amdgcn_cvt_pk_f32_fp8((d).y, false); U[4]  += f_[0]; U[5]  += f_[1];  \
  f_ = __builtin_amdgcn_cvt_pk_f32_fp8((d).y, true);  U[6]  += f_[0]; U[7]  += f_[1];  \
  f_ = __builtin_amdgcn_cvt_pk_f32_fp8((d).z, false); U[8]  += f_[0]; U[9]  += f_[1];  \
  f_ = __builtin_amdgcn_cvt_pk_f32_fp8((d).z, true);  U[10] += f_[0]; U[11] += f_[1];  \
  f_ = __builtin_amdgcn_cvt_pk_f32_fp8((d).w, false); U[12] += f_[0]; U[13] += f_[1];  \
  f_ = __builtin_amdgcn_cvt_pk_f32_fp8((d).w, true);  U[14] += f_[0]; U[15] += f_[1];  \
} while (0)

#define ACCSEL16(d, p) do {                      \
  if ((p) < o1)      { ACCUM16(u0, d); }         \
  else if ((p) < o2) { ACCUM16(u1, d); }         \
  else               { ACCUM16(u2, d); }         \
} while (0)

__global__ __launch_bounds__(256) void gather_xh_kernel(
    const u8* __restrict__ xq8, const int* __restrict__ off3, const int* __restrict__ ssrc,
    const int* __restrict__ spos, bf16* __restrict__ Ax, bf16* __restrict__ Ah,
    float4* __restrict__ cntf, int N)
{
  __shared__ alignas(16) bf16 lds[4][768];
  int w = threadIdx.x >> 6, lane = threadIdx.x & 63;
  int node = blockIdx.x * 4 + w;
  if (node >= N) return;
  int qt = lane >> 4, ql = lane & 15;
  int o0 = __builtin_amdgcn_readfirstlane(off3[node * 3]);
  int o1 = __builtin_amdgcn_readfirstlane(off3[node * 3 + 1]);
  int o2 = __builtin_amdgcn_readfirstlane(off3[node * 3 + 2]);
  int o3 = __builtin_amdgcn_readfirstlane(off3[node * 3 + 3]);
  float inv = 1.0f / (float)(o3 - o0);
  const u8* base = xq8 + ql * 16;

  float u0[16], u1[16], u2[16];
  #pragma unroll
  for (int k = 0; k < 16; ++k) { u0[k] = 0.f; u1[k] = 0.f; u2[k] = 0.f; }

  const int e = o3, emax = o3 - 1;
  for (int i = o0; i < e; i += 16) {
    int p0 = i + qt, p1 = p0 + 4, p2 = p0 + 8, p3 = p0 + 12;
    // clamped index loads: 4 independent, always issued
    int t0 = ssrc[min(p0, emax)];
    int t1 = ssrc[min(p1, emax)];
    int t2 = ssrc[min(p2, emax)];
    int t3 = ssrc[min(p3, emax)];
    // guarded data loads: d stays zero past the end (fp8 0x00 -> 0.0f)
    int4 d0 = make_int4(0, 0, 0, 0), d1 = d0, d2 = d0, d3 = d0;
    if (p0 < e) d0 = *(const int4*)(base + (size_t)t0 * 256);
    if (p1 < e) d1 = *(const int4*)(base + (size_t)t1 * 256);
    if (p2 < e) d2 = *(const int4*)(base + (size_t)t2 * 256);
    if (p3 < e) d3 = *(const int4*)(base + (size_t)t3 * 256);
    ACCSEL16(d0, p0);
    ACCSEL16(d1, p1);
    ACCSEL16(d2, p2);
    ACCSEL16(d3, p3);
  }

  #pragma unroll
  for (int k = 0; k < 16; ++k) {
    u0[k] += __shfl_xor(u0[k], 16); u0[k] += __shfl_xor(u0[k], 32);
    u1[k] += __shfl_xor(u1[k], 16); u1[k] += __shfl_xor(u1[k], 32);
    u2[k] += __shfl_xor(u2[k], 16); u2[k] += __shfl_xor(u2[k], 32);
  }
  if (qt == 0) {
    bf16x8 p0, p1;
    int sb0 = (ql < 8) ? (ql * 16) : (384 + (ql - 8) * 16);
    #pragma unroll
    for (int k = 0; k < 8; ++k) { p0[k] = (bf16)(u0[k] * inv); p1[k] = (bf16)(u0[8 + k] * inv); }
    *(bf16x8*)&lds[w][sb0] = p0;
    *(bf16x8*)&lds[w][sb0 + 8] = p1;
    int sb1 = sb0 + 128;
    #pragma unroll
    for (int k = 0; k < 8; ++k) { p0[k] = (bf16)(u1[k] * inv); p1[k] = (bf16)(u1[8 + k] * inv); }
    *(bf16x8*)&lds[w][sb1] = p0;
    *(bf16x8*)&lds[w][sb1 + 8] = p1;
    int sb2 = sb0 + 256;
    #pragma unroll
    for (int k = 0; k < 8; ++k) { p0[k] = (bf16)(u2[k] * inv); p1[k] = (bf16)(u2[8 + k] * inv); }
    *(bf16x8*)&lds[w][sb2] = p0;
    *(bf16x8*)&lds[w][sb2 + 8] = p1;
  }

  int t = spos[node];
  if (lane < 48) {
    size_t unit = (size_t)(t >> 4) * 1024 + lane * 16 + (t & 15);
    ((bf16x8*)Ax)[unit] = *(const bf16x8*)&lds[w][lane * 8];
    ((bf16x8*)Ah)[unit] = *(const bf16x8*)&lds[w][384 + lane * 8];
  }
  if (lane == 0)
    cntf[t] = make_float4((o1 - o0) * inv, (o2 - o1) * inv, (o3 - o2) * inv, (float)(o3 - o0));
}

#define ACCUM8(U, d) do { f32x2 f_;                                                  \
  f_ = __builtin_amdgcn_cvt_pk_f32_fp8((d).x, false); U[0] += f_[0]; U[1] += f_[1];  \
  f_ = __builtin_amdgcn_cvt_pk_f32_fp8((d).x, true);  U[2] += f_[0]; U[3] += f_[1];  \
  f_ = __builtin_amdgcn_cvt_pk_f32_fp8((d).y, false); U[4] += f_[0]; U[5] += f_[1];  \
  f_ = __builtin_amdgcn_cvt_pk_f32_fp8((d).y, true);  U[6] += f_[0]; U[7] += f_[1];  \
} while (0)

#define ACCSEL8(d, p) do {                      \
  if ((p) < o1)      { ACCUM8(v0, d); }         \
  else if ((p) < o2) { ACCUM8(v1, d); }         \
  else               { ACCUM8(v2, d); }         \
} while (0)

__global__ __launch_bounds__(256) void gather_q_kernel(
    const u8* __restrict__ q8, const int* __restrict__ off3, const int* __restrict__ ssrc,
    const int* __restrict__ spos, bf16* __restrict__ Aq, int N)
{
  __shared__ alignas(16) bf16 lds[4][384];
  int w = threadIdx.x >> 6, lane = threadIdx.x & 63;
  int node = blockIdx.x * 4 + w;
  if (node >= N) return;
  int qt = lane >> 4, ql = lane & 15;
  int o0 = __builtin_amdgcn_readfirstlane(off3[node * 3]);
  int o1 = __builtin_amdgcn_readfirstlane(off3[node * 3 + 1]);
  int o2 = __builtin_amdgcn_readfirstlane(off3[node * 3 + 2]);
  int o3 = __builtin_amdgcn_readfirstlane(off3[node * 3 + 3]);
  float inv = 1.0f / (float)(o3 - o0);
  const u8* base = q8 + ql * 8;

  float v0[8], v1[8], v2[8];
  #pragma unroll
  for (int k = 0; k < 8; ++k) { v0[k] = 0.f; v1[k] = 0.f; v2[k] = 0.f; }

  const int e = o3, emax = o3 - 1;
  for (int i = o0; i < e; i += 16) {
    int p0 = i + qt, p1 = p0 + 4, p2 = p0 + 8, p3 = p0 + 12;
    int t0 = ssrc[min(p0, emax)];
    int t1 = ssrc[min(p1, emax)];
    int t2 = ssrc[min(p2, emax)];
    int t3 = ssrc[min(p3, emax)];
    int2 d0 = make_int2(0, 0), d1 = d0, d2 = d0, d3 = d0;
    if (p0 < e) d0 = *(const int2*)(base + (size_t)t0 * 128);
    if (p1 < e) d1 = *(const int2*)(base + (size_t)t1 * 128);
    if (p2 < e) d2 = *(const int2*)(base + (size_t)t2 * 128);
    if (p3 < e) d3 = *(const int2*)(base + (size_t)t3 * 128);
    ACCSEL8(d0, p0);
    ACCSEL8(d1, p1);
    ACCSEL8(d2, p2);
    ACCSEL8(d3, p3);
  }

  #pragma unroll
  for (int k = 0; k < 8; ++k) {
    v0[k] += __shfl_xor(v0[k], 16); v0[k] += __shfl_xor(v0[k], 32);
    v1[k] += __shfl_xor(v1[k], 16); v1[k] += __shfl_xor(v1[k], 32);
    v2[k] += __shfl_xor(v2[k], 16); v2[k] += __shfl_xor(v2[k], 32);
  }
  if (qt == 0) {
    bf16x8 pk;
    #pragma unroll
    for (int k = 0; k < 8; ++k) pk[k] = (bf16)(v0[k] * inv);
    *(bf16x8*)&lds[w][ql * 8] = pk;
    #pragma unroll
    for (int k = 0; k < 8; ++k) pk[k] = (bf16)(v1[k] * inv);
    *(bf16x8*)&lds[w][128 + ql * 8] = pk;
    #pragma unroll
    for (int k = 0; k < 8; ++k) pk[k] = (bf16)(v2[k] * inv);
    *(bf16x8*)&lds[w][256 + ql * 8] = pk;
  }

  int t = spos[node];
  if (lane < 48) {
    size_t unit = (size_t)(t >> 4) * 1024 + lane * 16 + (t & 15);
    ((bf16x8*)Aq)[unit] = *(const bf16x8*)&lds[w][lane * 8];
  }
}

// ---------------- streaming MFMA GEMM (no LDS/barriers; 4 row-blocks per wave) ----------------
struct GArgs {
  const bf16* Ap[5];
  const bf16* wf[5];
  const bf16* pf[5];
  bf16* out[5];
  const float* bias[5];
};

__global__ __launch_bounds__(256) void gemm_kernel(GArgs ga, const float4* __restrict__ cntf,
                                                   const int* __restrict__ roleinfo)
{
  const int cv = blockIdx.y;
  const bf16* __restrict__ Ap = ga.Ap[cv];
  const bf16* __restrict__ wf = ga.wf[cv];
  const bf16* __restrict__ pf = ga.pf[cv];
  bf16* __restrict__ out = ga.out[cv];
  const float* __restrict__ bias = ga.bias[cv];

  const int w = threadIdx.x >> 6, lane = threadIdx.x & 63;
  const int q = lane >> 4, l = lane & 15;
  const int rb0 = blockIdx.x * 16 + w * 4;
  const int row0 = blockIdx.x * 256;
  const int s1 = roleinfo[0], s2 = roleinfo[1];
  const int role = (row0 >= s2) ? 2 : (row0 >= s1) ? 1 : 0;
  const int laneoff = q * 128 + l;

  f32x4 acc[4][8];
  #pragma unroll
  for (int j = 0; j < 4; ++j)
    #pragma unroll
    for (int ct = 0; ct < 8; ++ct)
      #pragma unroll
      for (int k = 0; k < 4; ++k) acc[j][ct][k] = 0.f;

  const bf16x8* A0 = (const bf16x8*)Ap + (size_t)rb0 * 1024 + lane;
  const bf16x8* WF = (const bf16x8*)wf + laneoff;
  const bf16x8* PF = (const bf16x8*)pf + role * 2048 + laneoff;

  #pragma unroll 2
  for (int ks = 0; ks < 16; ++ks) {
    const bf16x8* bp = (ks < 12) ? (WF + ks * 512) : (PF + (ks - 12) * 512);
    bf16x8 a0 = A0[ks * 64];
    bf16x8 a1 = A0[1024 + ks * 64];
    bf16x8 a2 = A0[2048 + ks * 64];
    bf16x8 a3 = A0[3072 + ks * 64];
    #pragma unroll
    for (int ct = 0; ct < 8; ++ct) {
      bf16x8 b = bp[ct * 16];
      acc[0][ct] = __builtin_amdgcn_mfma_f32_16x16x32_bf16(a0, b, acc[0][ct], 0, 0, 0);
      acc[1][ct] = __builtin_amdgcn_mfma_f32_16x16x32_bf16(a1, b, acc[1][ct], 0, 0, 0);
      acc[2][ct] = __builtin_amdgcn_mfma_f32_16x16x32_bf16(a2, b, acc[2][ct], 0, 0, 0);
      acc[3][ct] = __builtin_amdgcn_mfma_f32_16x16x32_bf16(a3, b, acc[3][ct], 0, 0, 0);
    }
  }

  const bool hb = (bias != nullptr);
  #pragma unroll
  for (int j = 0; j < 4; ++j) {
    int rb = rb0 + j;
    float4 cfs[4];
    if (hb) {
      #pragma unroll
      for (int reg = 0; reg < 4; ++reg) cfs[reg] = cntf[rb * 16 + q * 4 + reg];
    }
    #pragma unroll
    for (int ct = 0; ct < 8; ++ct) {
      int col = ct * 16 + l;
      float b0 = 0, b1 = 0, b2 = 0;
      if (hb) { b0 = bias[col]; b1 = bias[128 + col]; b2 = bias[256 + col]; }
      #pragma unroll
      for (int reg = 0; reg < 4; ++reg) {
        int t = rb * 16 + q * 4 + reg;
        float v = acc[j][ct][reg];
        if (hb) v += cfs[reg].x * b0 + cfs[reg].y * b1 + cfs[reg].z * b2;
        out[(size_t)t * 128 + col] = (bf16)fmaxf(v, 0.f);
      }
    }
  }
}

// ---------------- combines ----------------
__global__ __launch_bounds__(256) void combine1_kernel(
    const bf16* __restrict__ o0, const bf16* __restrict__ o1,
    const bf16* __restrict__ o2, const bf16* __restrict__ o3,
    const float* __restrict__ h, const int* __restrict__ spos,
    float* __restrict__ zbuf, u8* __restrict__ q8, bf16* __restrict__ Aq, int N)
{
  int g = blockIdx.x * 256 + threadIdx.x;
  if (g >= N * 16) return;
  int n = g >> 4, o = g & 15;
  int t = spos[n];
  size_t tb = (size_t)t * 16 + o;
  bf16x8 a0 = ((const bf16x8*)o0)[tb];
  bf16x8 a1 = ((const bf16x8*)o1)[tb];
  bf16x8 a2 = ((const bf16x8*)o2)[tb];
  bf16x8 a3 = ((const bf16x8*)o3)[tb];
  size_t nb = (size_t)n * 16 + o;
  float4 h0 = ((const float4*)h)[nb * 2];
  float4 h1 = ((const float4*)h)[nb * 2 + 1];
  float hv[8] = {h0.x, h0.y, h0.z, h0.w, h1.x, h1.y, h1.z, h1.w};
  float zv[8], qv[8];
  bf16x8 qb;
  #pragma unroll
  for (int j = 0; j < 8; ++j) {
    zv[j] = sigmoidf_((float)a0[j] + (float)a1[j]);
    qv[j] = sigmoidf_((float)a2[j] + (float)a3[j]) * hv[j];
    qb[j] = (bf16)qv[j];
  }
  ((float4*)zbuf)[nb * 2]     = make_float4(zv[0], zv[1], zv[2], zv[3]);
  ((float4*)zbuf)[nb * 2 + 1] = make_float4(zv[4], zv[5], zv[6], zv[7]);
  int lo = __builtin_amdgcn_cvt_pk_fp8_f32(qv[0], qv[1], 0, false);
  lo = __builtin_amdgcn_cvt_pk_fp8_f32(qv[2], qv[3], lo, true);
  int hi = __builtin_amdgcn_cvt_pk_fp8_f32(qv[4], qv[5], 0, false);
  hi = __builtin_amdgcn_cvt_pk_fp8_f32(qv[6], qv[7], hi, true);
  *(int2*)(q8 + (size_t)t * 128 + o * 8) = make_int2(lo, hi);
  size_t unit = (size_t)(t >> 4) * 1024 + (48 + o) * 16 + (t & 15);
  ((bf16x8*)Aq)[unit] = qb;
}

__global__ __launch_bounds__(256) void combine2_kernel(
    const float* __restrict__ zbuf, const bf16* __restrict__ o4, const bf16* __restrict__ o5,
    const float* __restrict__ h, const int* __restrict__ spos, float* __restrict__ out, int N)
{
  int g = blockIdx.x * 256 + threadIdx.x;
  if (g >= N * 16) return;
  int n = g >> 4, o = g & 15;
  int t = spos[n];
  size_t tb = (size_t)t * 16 + o;
  bf16x8 a = ((const bf16x8*)o4)[tb];
  bf16x8 b = ((const bf16x8*)o5)[tb];
  size_t nb = (size_t)n * 16 + o;
  float4 z0 = ((const float4*)zbuf)[nb * 2];
  float4 z1 = ((const float4*)zbuf)[nb * 2 + 1];
  float4 h0 = ((const float4*)h)[nb * 2];
  float4 h1 = ((const float4*)h)[nb * 2 + 1];
  float zv[8] = {z0.x, z0.y, z0.z, z0.w, z1.x, z1.y, z1.z, z1.w};
  float hv[8] = {h0.x, h0.y, h0.z, h0.w, h1.x, h1.y, h1.z, h1.w};
  float ov[8];
  #pragma unroll
  for (int j = 0; j < 8; ++j)
    ov[j] = zv[j] * hv[j] + (1.f - zv[j]) * tanhf((float)a[j] + (float)b[j]);
  ((float4*)out)[nb * 2]     = make_float4(ov[0], ov[1], ov[2], ov[3]);
  ((float4*)out)[nb * 2 + 1] = make_float4(ov[4], ov[5], ov[6], ov[7]);
}

// ---------------- host ----------------
extern "C" void kernel_launch(void* const* d_in, const int* in_sizes, int n_in,
                              void* d_out, int out_size, void* d_ws, size_t ws_size,
                              hipStream_t stream)
{
  (void)n_in; (void)out_size; (void)ws_size;
  const float* x    = (const float*)d_in[0];
  const float* h    = (const float*)d_in[1];
  const int*   ei   = (const int*)d_in[2];
  const int*   role = (const int*)d_in[3];
  const int N = in_sizes[0] / DH;
  const int E = in_sizes[2] / 2;
  const int Etot = E + N;
  const int rows_pad = ((N + 765) + 255) & ~255;
  const int gx = rows_pad / 256;
  const int n3 = N * 3;
  const int nb3 = (n3 + 1023) / 1024;

  // conv order: 0 xz, 1 hz, 2 xr, 3 hr, 4 xh, 5 hh
  static const int Wi[6]  = {4, 9, 13, 18, 22, 27};
  static const int Wgi[6] = {5, 10, 14, 19, 23, 28};
  static const int bgi[6] = {6, 11, 15, 20, 24, 29};
  static const int Si[6]  = {7, 12, 16, 21, 25, 30};

  char* p = (char*)d_ws;
  auto alloc = [&](size_t bytes) -> char* {
    char* r = p;
    p += (bytes + 255) & ~(size_t)255;
    return r;
  };

  bf16* Ax = (bf16*)alloc((size_t)rows_pad * 512 * 2);   // Aq aliases Ax
  bf16* Ah = (bf16*)alloc((size_t)rows_pad * 512 * 2);
  bf16* Aq = Ax;
  u8* xq8  = (u8*)alloc((size_t)rows_pad * 256);
  u8* q8   = (u8*)alloc((size_t)rows_pad * 128);
  bf16* outs[6];
  for (int c = 0; c < 5; ++c) outs[c] = (bf16*)alloc((size_t)rows_pad * 128 * 2);
  outs[5] = outs[0];
  float* zbuf = (float*)alloc((size_t)N * 128 * 4);
  float4* cntf = (float4*)alloc((size_t)rows_pad * 16);
  bf16* Wf = (bf16*)alloc((size_t)6 * 49152 * 2);
  bf16* Pf = (bf16*)alloc((size_t)18 * 16384 * 2);
  int* cnt3  = (int*)alloc((size_t)n3 * 4);
  int* off3  = (int*)alloc((size_t)(n3 + 1) * 4);
  int* fill3 = (int*)alloc((size_t)n3 * 4);
  int* bsum  = (int*)alloc((size_t)(nb3 + 1) * 4);
  int* ssrc  = (int*)alloc((size_t)Etot * 4);
  int* spos  = (int*)alloc((size_t)N * 4);
  int* rolecnt  = (int*)alloc(64);
  int* rolefill = (int*)alloc(64);
  int* roleinfo = (int*)alloc(64);

  hipMemsetAsync(cnt3, 0, (size_t)n3 * 4, stream);
  hipMemsetAsync(rolecnt, 0, 16, stream);

  int egrid = (Etot + 255) / 256;
  int ngrid = (N + 255) / 256;
  hist_kernel<<<egrid, 256, 0, stream>>>(ei, role, cnt3, rolecnt, E, N);
  scan1_kernel<<<nb3, 1024, 0, stream>>>(cnt3, off3, bsum, n3);
  scan2_kernel<<<1, 64, 0, stream>>>(bsum, nb3, rolecnt, rolefill, roleinfo);
  scan3_kernel<<<nb3, 1024, 0, stream>>>(off3, fill3, bsum, n3);
  permscatter_kernel<<<ngrid, 256, 0, stream>>>(role, rolefill, spos, N);
  scatter_kernel<<<egrid, 256, 0, stream>>>(ei, spos, roleinfo, fill3, ssrc, E, N);
  zeropad_kernel<<<384, 256, 0, stream>>>(roleinfo, Ax, Ah);

  prep_xh_kernel<<<(N * 32 + 255) / 256, 256, 0, stream>>>(x, h, spos, xq8, Ax, Ah, N);

  PrepW pw;
  for (int c = 0; c < 6; ++c) {
    pw.W[c] = (const float*)d_in[Wi[c]];
    pw.Wg[c] = (const float*)d_in[Wgi[c]];
    pw.bg[c] = (const float*)d_in[bgi[c]];
  }
  prep_wf_kernel<<<1152, 256, 0, stream>>>(pw, Wf);
  PrepP pp;
  for (int c = 0; c < 6; ++c) { pp.W[c] = (const float*)d_in[Wi[c]]; pp.S[c] = (const float*)d_in[Si[c]]; }
  prep_pf_kernel<<<2304, 128, 0, stream>>>(pp, Pf);

  gather_xh_kernel<<<(N + 3) / 4, 256, 0, stream>>>(xq8, off3, ssrc, spos, Ax, Ah, cntf, N);

  // pass 1: one dispatch, cv 0..4 = {xz,xr,xh on Ax (bias)} + {hz,hr on Ah}
  GArgs g0;
  { int cvs[5] = {0, 2, 4, 1, 3};
    static const int bi2[5] = {8, 17, 26, -1, -1};
    const bf16* Apts[5] = {Ax, Ax, Ax, Ah, Ah};
    for (int k = 0; k < 5; ++k) {
      int c = cvs[k];
      g0.Ap[k] = Apts[k];
      g0.wf[k] = Wf + (size_t)c * 49152;
      g0.pf[k] = Pf + (size_t)c * 3 * 16384;
      g0.out[k] = outs[c];
      g0.bias[k] = (bi2[k] >= 0) ? (const float*)d_in[bi2[k]] : nullptr;
    } }
  gemm_kernel<<<dim3(gx, 5), 256, 0, stream>>>(g0, cntf, roleinfo);

  combine1_kernel<<<(N * 16 + 255) / 256, 256, 0, stream>>>(outs[0], outs[1], outs[2], outs[3],
                                                            h, spos, zbuf, q8, Aq, N);

  gather_q_kernel<<<(N + 3) / 4, 256, 0, stream>>>(q8, off3, ssrc, spos, Aq, N);

  // pass 2: conv hh(5) on Aq
  GArgs g2 = {};
  g2.Ap[0] = Aq;
  g2.wf[0] = Wf + (size_t)5 * 49152;
  g2.pf[0] = Pf + (size_t)5 * 3 * 16384;
  g2.out[0] = outs[5];
  g2.bias[0] = nullptr;
  gemm_kernel<<<dim3(gx, 1), 256, 0, stream>>>(g2, cntf, roleinfo);

  combine2_kernel<<<(N * 16 + 255) / 256, 256, 0, stream>>>(zbuf, outs[4], outs[5], h, spos,
                                                            (float*)d_out, N);
}

// Round 3
// 730.017 us; speedup vs baseline: 1.0553x; 1.0360x over previous
//
#include <hip/hip_runtime.h>

// GraphGRU on MI355X — round 9.
//   Gathers are memory-system-throughput bound (r8: +ILP changed nothing; 317 MB @ 2.42 TB/s).
//   This round reduces bytes: gather blocks remapped to t-order (8 consecutive rows per
//   512-thread block, via sposinv) with cooperative full-128B-line A-writes staged in LDS,
//   issued as non-temporal stores (stop evicting xq8 from L2). GEMM & layout untouched.

typedef __bf16 bf16;
typedef __bf16 bf16x8 __attribute__((ext_vector_type(8)));
typedef float  f32x4  __attribute__((ext_vector_type(4)));
typedef float  f32x2  __attribute__((ext_vector_type(2)));
typedef unsigned char u8;

#define DH 128

__device__ __forceinline__ float sigmoidf_(float x) { return 1.0f / (1.0f + expf(-x)); }

// ---------------- CSR build ----------------
__global__ __launch_bounds__(256) void hist_kernel(const int* __restrict__ ei, const int* __restrict__ role,
                                                   int* __restrict__ cnt3, int* __restrict__ rolecnt,
                                                   int E, int N)
{
  int i = blockIdx.x * 256 + threadIdx.x;
  int lane = threadIdx.x & 63;
  int r = (i < N) ? role[i] : -1;
  #pragma unroll
  for (int rr = 0; rr < 3; ++rr) {
    unsigned long long mask = __ballot(r == rr);
    if (lane == 0 && mask) atomicAdd(&rolecnt[rr], __popcll(mask));
  }
  if (i < E + N) {
    int src, dst;
    if (i < E) { src = ei[i]; dst = ei[E + i]; } else { src = i - E; dst = i - E; }
    int rs = (i < E) ? role[src] : r;
    if (i >= E) rs = role[i - E];
    atomicAdd(&cnt3[dst * 3 + rs], 1);
  }
}

__global__ __launch_bounds__(1024) void scan1_kernel(const int* __restrict__ cnt, int* __restrict__ off,
                                                     int* __restrict__ bsum, int n)
{
  __shared__ int wsum[16];
  int t = threadIdx.x, lane = t & 63, w = t >> 6;
  int idx = blockIdx.x * 1024 + t;
  int v = (idx < n) ? cnt[idx] : 0;
  int s = v;
  #pragma unroll
  for (int d = 1; d < 64; d <<= 1) { int u = __shfl_up(s, d); if (lane >= d) s += u; }
  if (lane == 63) wsum[w] = s;
  __syncthreads();
  if (w == 0 && lane < 16) {
    int ws = wsum[lane];
    #pragma unroll
    for (int d = 1; d < 16; d <<= 1) { int u = __shfl_up(ws, d); if (lane >= d) ws += u; }
    wsum[lane] = ws;
  }
  __syncthreads();
  int inc = ((w > 0) ? wsum[w - 1] : 0) + s;
  if (idx < n) off[idx + 1] = inc;
  if (t == 1023) bsum[blockIdx.x] = inc;
}

__global__ void scan2_kernel(int* __restrict__ bsum, int nb, const int* __restrict__ rolecnt,
                             int* __restrict__ rolefill, int* __restrict__ roleinfo)
{
  int lane = threadIdx.x;
  int carry = 0;
  for (int base = 0; base < nb; base += 64) {
    int v = (base + lane < nb) ? bsum[base + lane] : 0;
    int s = v;
    #pragma unroll
    for (int d = 1; d < 64; d <<= 1) { int u = __shfl_up(s, d); if (lane >= d) s += u; }
    if (base + lane < nb) bsum[base + lane] = carry + s - v;
    carry += __shfl(s, 63);
  }
  if (lane == 0) {
    int c0 = rolecnt[0], c1 = rolecnt[1], c2 = rolecnt[2];
    int s1 = (c0 + 255) & ~255;
    int s2 = s1 + ((c1 + 255) & ~255);
    int mp = s2 + ((c2 + 255) & ~255);
    rolefill[0] = 0; rolefill[1] = s1; rolefill[2] = s2;
    roleinfo[0] = s1; roleinfo[1] = s2;
    roleinfo[2] = c0;      roleinfo[3] = s1 - c0;
    roleinfo[4] = s1 + c1; roleinfo[5] = s2 - s1 - c1;
    roleinfo[6] = s2 + c2; roleinfo[7] = mp - s2 - c2;
  }
}

__global__ __launch_bounds__(1024) void scan3_kernel(int* __restrict__ off, int* __restrict__ fill,
                                                     const int* __restrict__ bsum, int n)
{
  int idx = blockIdx.x * 1024 + threadIdx.x;
  if (idx == 0) { off[0] = 0; fill[0] = 0; }
  if (idx < n) {
    int v = off[idx + 1] + bsum[blockIdx.x];
    off[idx + 1] = v;
    if (idx + 1 < n) fill[idx + 1] = v;
  }
}

__global__ __launch_bounds__(256) void scatter_kernel(const int* __restrict__ ei, const int* __restrict__ spos,
                                                      const int* __restrict__ roleinfo,
                                                      int* __restrict__ fill3, int* __restrict__ ssrc, int E, int N)
{
  int i = blockIdx.x * 256 + threadIdx.x;
  if (i >= E + N) return;
  int s1 = roleinfo[0], s2 = roleinfo[1];
  int src, dst;
  if (i < E) { src = ei[i]; dst = ei[E + i]; } else { src = i - E; dst = i - E; }
  int t = spos[src];
  int r = (t >= s2) ? 2 : (t >= s1) ? 1 : 0;
  int pz = atomicAdd(&fill3[dst * 3 + r], 1);
  ssrc[pz] = t;
}

__global__ __launch_bounds__(256) void permscatter_kernel(const int* __restrict__ role, int* __restrict__ rolefill,
                                                          int* __restrict__ spos, int* __restrict__ sposinv, int N)
{
  int i = blockIdx.x * 256 + threadIdx.x;
  int lane = threadIdx.x & 63;
  int r = (i < N) ? role[i] : -1;
  #pragma unroll
  for (int rr = 0; rr < 3; ++rr) {
    unsigned long long mask = __ballot(r == rr);
    if (!mask) continue;
    int base = 0;
    if (lane == 0) base = atomicAdd(&rolefill[rr], __popcll(mask));
    base = __shfl(base, 0);
    if (r == rr) {
      int rank = (int)__popcll(mask & ((1ull << lane) - 1ull));
      int pos = base + rank;
      spos[i] = pos;
      sposinv[pos] = i;
    }
  }
}

__global__ __launch_bounds__(256) void zeropad_kernel(const int* __restrict__ roleinfo,
                                                      bf16* __restrict__ Ax, bf16* __restrict__ Ah)
{
  int id = blockIdx.x * 256 + threadIdx.x;   // 98304
  int a = id / 49152, rem = id % 49152;
  int gp = rem / 16384, r2 = rem % 16384;
  int rr = r2 >> 6, c = r2 & 63;
  int gs = roleinfo[2 + gp * 2], gl = roleinfo[3 + gp * 2];
  if (rr < gl) {
    int row = gs + rr;
    size_t unit = (size_t)(row >> 4) * 1024 + c * 16 + (row & 15);
    bf16x8 z = {};
    ((bf16x8*)(a == 0 ? Ax : Ah))[unit] = z;
  }
}

// ---------------- prep ----------------
__global__ __launch_bounds__(256) void prep_xh_kernel(const float* __restrict__ x, const float* __restrict__ h,
                                                      const int* __restrict__ spos, u8* __restrict__ xq8,
                                                      bf16* __restrict__ Ax, bf16* __restrict__ Ah, int N)
{
  int g = blockIdx.x * 256 + threadIdx.x;
  if (g >= N * 32) return;
  int n = g >> 5, j = g & 31;
  int t = spos[n];
  const float* src = (j < 16) ? (x + (size_t)n * 128 + (j << 3))
                              : (h + (size_t)n * 128 + ((j - 16) << 3));
  float4 v0 = ((const float4*)src)[0];
  float4 v1 = ((const float4*)src)[1];
  int lo = __builtin_amdgcn_cvt_pk_fp8_f32(v0.x, v0.y, 0, false);
  lo = __builtin_amdgcn_cvt_pk_fp8_f32(v0.z, v0.w, lo, true);
  int hi = __builtin_amdgcn_cvt_pk_fp8_f32(v1.x, v1.y, 0, false);
  hi = __builtin_amdgcn_cvt_pk_fp8_f32(v1.z, v1.w, hi, true);
  *(int2*)(xq8 + (size_t)t * 256 + j * 8) = make_int2(lo, hi);
  bf16x8 o;
  o[0] = (bf16)v0.x; o[1] = (bf16)v0.y; o[2] = (bf16)v0.z; o[3] = (bf16)v0.w;
  o[4] = (bf16)v1.x; o[5] = (bf16)v1.y; o[6] = (bf16)v1.z; o[7] = (bf16)v1.w;
  size_t unit = (size_t)(t >> 4) * 1024 + (48 + (j & 15)) * 16 + (t & 15);
  ((bf16x8*)(j < 16 ? Ax : Ah))[unit] = o;
}

struct PrepW { const float* W[6]; const float* Wg[6]; const float* bg[6]; };
__global__ __launch_bounds__(256) void prep_wf_kernel(PrepW pw, bf16* __restrict__ Wf)
{
  int idx = blockIdx.x * 256 + threadIdx.x;
  if (idx >= 294912) return;
  int cv = idx / 49152, pos = idx % 49152;
  int ks4q = pos >> 10;
  int col = (pos >> 3) & 127, j = pos & 7;
  int k = (ks4q >> 2) * 32 + (ks4q & 3) * 8 + j;
  int r = k >> 7, kk = k & 127;
  float g = sigmoidf_(pw.Wg[cv][r * 128 + col] + pw.bg[cv][r * 128 + col]);
  Wf[idx] = (bf16)(pw.W[cv][kk * 128 + col] * g);
}

struct PrepP { const float* W[6]; const float* S[6]; };
__global__ __launch_bounds__(128) void prep_pf_kernel(PrepP pp, bf16* __restrict__ Pf)
{
  int b = blockIdx.x;                          // 6*3*128
  int cv = b / 384, rem = b % 384;
  int r = rem >> 7, kp = rem & 127;
  int col = threadIdx.x;
  const float* W = pp.W[cv] + (size_t)kp * 128;
  const float* S = pp.S[cv] + (size_t)r * 16384;
  float sum = 0.f;
  #pragma unroll 4
  for (int j2 = 0; j2 < 128; ++j2) sum += W[j2] * S[j2 * 128 + col];
  size_t o = (size_t)(cv * 3 + r) * 16384 + ((size_t)(kp >> 3) * 128 + col) * 8 + (kp & 7);
  Pf[o] = (bf16)sum;
}

// ---------------- gathers (t-ordered 8-node blocks, cooperative full-line NT writes) ----------------
#define ACCUM16(U, d) do { f32x2 f_;                                                   \
  f_ = __builtin_amdgcn_cvt_pk_f32_fp8((d).x, false); U[0]  += f_[0]; U[1]  += f_[1];  \
  f_ = __builtin_amdgcn_cvt_pk_f32_fp8((d).x, true);  U[2]  += f_[0]; U[3]  += f_[1];  \
  f_ = __builtin_amdgcn_cvt_pk_f32_fp8((d).y, false); U[4]  += f_[0]; U[5]  += f_[1];  \
  f_ = __builtin_amdgcn_cvt_pk_f32_fp8((d).y, true);  U[6]  += f_[0]; U[7]  += f_[1];  \
  f_ = __builtin_amdgcn_cvt_pk_f32_fp8((d).z, false); U[8]  += f_[0]; U[9]  += f_[1];  \
  f_ = __builtin_amdgcn_cvt_pk_f32_fp8((d).z, true);  U[10] += f_[0]; U[11] += f_[1];  \
  f_ = __builtin_amdgcn_cvt_pk_f32_fp8((d).w, false); U[12] += f_[0]; U[13] += f_[1];  \
  f_ = __builtin_amdgcn_cvt_pk_f32_fp8((d).w, true);  U[14] += f_[0]; U[15] += f_[1];  \
} while (0)

#define ACCSEL16(d, p) do {                      \
  if ((p) < o1)      { ACCUM16(u0, d); }         \
  else if ((p) < o2) { ACCUM16(u1, d); }         \
  else               { ACCUM16(u2, d); }         \
} while (0)

__global__ __launch_bounds__(512) void gather_xh_kernel(
    const u8* __restrict__ xq8, const int* __restrict__ off3, const int* __restrict__ ssrc,
    const int* __restrict__ sposinv, bf16* __restrict__ Ax, bf16* __restrict__ Ah,
    float4* __restrict__ cntf)
{
  __shared__ alignas(16) bf16 lds[8][768];
  int w = threadIdx.x >> 6, lane = threadIdx.x & 63;
  int t0 = blockIdx.x * 8;
  int t = t0 + w;
  int node = sposinv[t];                 // -1 for pad rows
  int qt = lane >> 4, ql = lane & 15;

  if (node >= 0) {
    int o0 = __builtin_amdgcn_readfirstlane(off3[node * 3]);
    int o1 = __builtin_amdgcn_readfirstlane(off3[node * 3 + 1]);
    int o2 = __builtin_amdgcn_readfirstlane(off3[node * 3 + 2]);
    int o3 = __builtin_amdgcn_readfirstlane(off3[node * 3 + 3]);
    float inv = 1.0f / (float)(o3 - o0);
    const u8* base = xq8 + ql * 16;

    float u0[16], u1[16], u2[16];
    #pragma unroll
    for (int k = 0; k < 16; ++k) { u0[k] = 0.f; u1[k] = 0.f; u2[k] = 0.f; }

    const int e = o3, emax = o3 - 1;
    for (int i = o0; i < e; i += 16) {
      int p0 = i + qt, p1 = p0 + 4, p2 = p0 + 8, p3 = p0 + 12;
      int t0i = ssrc[min(p0, emax)];
      int t1i = ssrc[min(p1, emax)];
      int t2i = ssrc[min(p2, emax)];
      int t3i = ssrc[min(p3, emax)];
      int4 d0 = make_int4(0, 0, 0, 0), d1 = d0, d2 = d0, d3 = d0;
      if (p0 < e) d0 = *(const int4*)(base + (size_t)t0i * 256);
      if (p1 < e) d1 = *(const int4*)(base + (size_t)t1i * 256);
      if (p2 < e) d2 = *(const int4*)(base + (size_t)t2i * 256);
      if (p3 < e) d3 = *(const int4*)(base + (size_t)t3i * 256);
      ACCSEL16(d0, p0);
      ACCSEL16(d1, p1);
      ACCSEL16(d2, p2);
      ACCSEL16(d3, p3);
    }

    #pragma unroll
    for (int k = 0; k < 16; ++k) {
      u0[k] += __shfl_xor(u0[k], 16); u0[k] += __shfl_xor(u0[k], 32);
      u1[k] += __shfl_xor(u1[k], 16); u1[k] += __shfl_xor(u1[k], 32);
      u2[k] += __shfl_xor(u2[k], 16); u2[k] += __shfl_xor(u2[k], 32);
    }
    if (qt == 0) {
      bf16x8 p0v, p1v;
      int sb0 = (ql < 8) ? (ql * 16) : (384 + (ql - 8) * 16);
      #pragma unroll
      for (int k = 0; k < 8; ++k) { p0v[k] = (bf16)(u0[k] * inv); p1v[k] = (bf16)(u0[8 + k] * inv); }
      *(bf16x8*)&lds[w][sb0] = p0v;
      *(bf16x8*)&lds[w][sb0 + 8] = p1v;
      #pragma unroll
      for (int k = 0; k < 8; ++k) { p0v[k] = (bf16)(u1[k] * inv); p1v[k] = (bf16)(u1[8 + k] * inv); }
      *(bf16x8*)&lds[w][sb0 + 128] = p0v;
      *(bf16x8*)&lds[w][sb0 + 136] = p1v;
      #pragma unroll
      for (int k = 0; k < 8; ++k) { p0v[k] = (bf16)(u2[k] * inv); p1v[k] = (bf16)(u2[8 + k] * inv); }
      *(bf16x8*)&lds[w][sb0 + 256] = p0v;
      *(bf16x8*)&lds[w][sb0 + 264] = p1v;
    }
    if (lane == 0)
      cntf[t] = make_float4((o1 - o0) * inv, (o2 - o1) * inv, (o3 - o2) * inv, (float)(o3 - o0));
  } else {
    // pad row: zero-fill this wave's LDS section so the cooperative write stores zeros
    if (lane < 48) {
      bf16x8 z = {};
      *(bf16x8*)&lds[w][lane * 16] = z;
      *(bf16x8*)&lds[w][lane * 16 + 8] = z;
    }
    if (lane == 0) cntf[t] = make_float4(0.f, 0.f, 0.f, 0.f);
  }

  __syncthreads();

  // cooperative write: 8 consecutive rows (t0..t0+7, same 16-group) -> full 128-B lines
  int tid = threadIdx.x;
  if (tid < 384) {
    int lc = tid >> 3, row = tid & 7;
    size_t unit = (size_t)(t0 >> 4) * 1024 + lc * 16 + (t0 & 15) + row;
    __builtin_nontemporal_store(*(const bf16x8*)&lds[row][lc * 8], (bf16x8*)Ax + unit);
    __builtin_nontemporal_store(*(const bf16x8*)&lds[row][384 + lc * 8], (bf16x8*)Ah + unit);
  }
}

#define ACCUM8(U, d) do { f32x2 f_;                                                  \
  f_ = __builtin_amdgcn_cvt_pk_f32_fp8((d).x, false); U[0] += f_[0]; U[1] += f_[1];  \
  f_ = __builtin_amdgcn_cvt_pk_f32_fp8((d).x, true);  U[2] += f_[0]; U[3] += f_[1];  \
  f_ = __builtin_amdgcn_cvt_pk_f32_fp8((d).y, false); U[4] += f_[0]; U[5] += f_[1];  \
  f_ = __builtin_amdgcn_cvt_pk_f32_fp8((d).y, true);  U[6] += f_[0]; U[7] += f_[1];  \
} while (0)

#define ACCSEL8(d, p) do {                      \
  if ((p) < o1)      { ACCUM8(v0, d); }         \
  else if ((p) < o2) { ACCUM8(v1, d); }         \
  else               { ACCUM8(v2, d); }         \
} while (0)

__global__ __launch_bounds__(512) void gather_q_kernel(
    const u8* __restrict__ q8, const int* __restrict__ off3, const int* __restrict__ ssrc,
    const int* __restrict__ sposinv, bf16* __restrict__ Aq)
{
  __shared__ alignas(16) bf16 lds[8][384];
  int w = threadIdx.x >> 6, lane = threadIdx.x & 63;
  int t0 = blockIdx.x * 8;
  int t = t0 + w;
  int node = sposinv[t];
  int qt = lane >> 4, ql = lane & 15;

  if (node >= 0) {
    int o0 = __builtin_amdgcn_readfirstlane(off3[node * 3]);
    int o1 = __builtin_amdgcn_readfirstlane(off3[node * 3 + 1]);
    int o2 = __builtin_amdgcn_readfirstlane(off3[node * 3 + 2]);
    int o3 = __builtin_amdgcn_readfirstlane(off3[node * 3 + 3]);
    float inv = 1.0f / (float)(o3 - o0);
    const u8* base = q8 + ql * 8;

    float v0[8], v1[8], v2[8];
    #pragma unroll
    for (int k = 0; k < 8; ++k) { v0[k] = 0.f; v1[k] = 0.f; v2[k] = 0.f; }

    const int e = o3, emax = o3 - 1;
    for (int i = o0; i < e; i += 16) {
      int p0 = i + qt, p1 = p0 + 4, p2 = p0 + 8, p3 = p0 + 12;
      int t0i = ssrc[min(p0, emax)];
      int t1i = ssrc[min(p1, emax)];
      int t2i = ssrc[min(p2, emax)];
      int t3i = ssrc[min(p3, emax)];
      int2 d0 = make_int2(0, 0), d1 = d0, d2 = d0, d3 = d0;
      if (p0 < e) d0 = *(const int2*)(base + (size_t)t0i * 128);
      if (p1 < e) d1 = *(const int2*)(base + (size_t)t1i * 128);
      if (p2 < e) d2 = *(const int2*)(base + (size_t)t2i * 128);
      if (p3 < e) d3 = *(const int2*)(base + (size_t)t3i * 128);
      ACCSEL8(d0, p0);
      ACCSEL8(d1, p1);
      ACCSEL8(d2, p2);
      ACCSEL8(d3, p3);
    }

    #pragma unroll
    for (int k = 0; k < 8; ++k) {
      v0[k] += __shfl_xor(v0[k], 16); v0[k] += __shfl_xor(v0[k], 32);
      v1[k] += __shfl_xor(v1[k], 16); v1[k] += __shfl_xor(v1[k], 32);
      v2[k] += __shfl_xor(v2[k], 16); v2[k] += __shfl_xor(v2[k], 32);
    }
    if (qt == 0) {
      bf16x8 pk;
      #pragma unroll
      for (int k = 0; k < 8; ++k) pk[k] = (bf16)(v0[k] * inv);
      *(bf16x8*)&lds[w][ql * 8] = pk;
      #pragma unroll
      for (int k = 0; k < 8; ++k) pk[k] = (bf16)(v1[k] * inv);
      *(bf16x8*)&lds[w][128 + ql * 8] = pk;
      #pragma unroll
      for (int k = 0; k < 8; ++k) pk[k] = (bf16)(v2[k] * inv);
      *(bf16x8*)&lds[w][256 + ql * 8] = pk;
    }
  } else {
    if (lane < 48) {
      bf16x8 z = {};
      *(bf16x8*)&lds[w][lane * 8] = z;
    }
  }

  __syncthreads();

  int tid = threadIdx.x;
  if (tid < 384) {
    int lc = tid >> 3, row = tid & 7;
    size_t unit = (size_t)(t0 >> 4) * 1024 + lc * 16 + (t0 & 15) + row;
    __builtin_nontemporal_store(*(const bf16x8*)&lds[row][lc * 8], (bf16x8*)Aq + unit);
  }
}

// ---------------- streaming MFMA GEMM (no LDS/barriers; 4 row-blocks per wave) ----------------
struct GArgs {
  const bf16* Ap[5];
  const bf16* wf[5];
  const bf16* pf[5];
  bf16* out[5];
  const float* bias[5];
};

__global__ __launch_bounds__(256) void gemm_kernel(GArgs ga, const float4* __restrict__ cntf,
                                                   const int* __restrict__ roleinfo)
{
  const int cv = blockIdx.y;
  const bf16* __restrict__ Ap = ga.Ap[cv];
  const bf16* __restrict__ wf = ga.wf[cv];
  const bf16* __restrict__ pf = ga.pf[cv];
  bf16* __restrict__ out = ga.out[cv];
  const float* __restrict__ bias = ga.bias[cv];

  const int w = threadIdx.x >> 6, lane = threadIdx.x & 63;
  const int q = lane >> 4, l = lane & 15;
  const int rb0 = blockIdx.x * 16 + w * 4;
  const int row0 = blockIdx.x * 256;
  const int s1 = roleinfo[0], s2 = roleinfo[1];
  const int role = (row0 >= s2) ? 2 : (row0 >= s1) ? 1 : 0;
  const int laneoff = q * 128 + l;

  f32x4 acc[4][8];
  #pragma unroll
  for (int j = 0; j < 4; ++j)
    #pragma unroll
    for (int ct = 0; ct < 8; ++ct)
      #pragma unroll
      for (int k = 0; k < 4; ++k) acc[j][ct][k] = 0.f;

  const bf16x8* A0 = (const bf16x8*)Ap + (size_t)rb0 * 1024 + lane;
  const bf16x8* WF = (const bf16x8*)wf + laneoff;
  const bf16x8* PF = (const bf16x8*)pf + role * 2048 + laneoff;

  #pragma unroll 2
  for (int ks = 0; ks < 16; ++ks) {
    const bf16x8* bp = (ks < 12) ? (WF + ks * 512) : (PF + (ks - 12) * 512);
    bf16x8 a0 = A0[ks * 64];
    bf16x8 a1 = A0[1024 + ks * 64];
    bf16x8 a2 = A0[2048 + ks * 64];
    bf16x8 a3 = A0[3072 + ks * 64];
    #pragma unroll
    for (int ct = 0; ct < 8; ++ct) {
      bf16x8 b = bp[ct * 16];
      acc[0][ct] = __builtin_amdgcn_mfma_f32_16x16x32_bf16(a0, b, acc[0][ct], 0, 0, 0);
      acc[1][ct] = __builtin_amdgcn_mfma_f32_16x16x32_bf16(a1, b, acc[1][ct], 0, 0, 0);
      acc[2][ct] = __builtin_amdgcn_mfma_f32_16x16x32_bf16(a2, b, acc[2][ct], 0, 0, 0);
      acc[3][ct] = __builtin_amdgcn_mfma_f32_16x16x32_bf16(a3, b, acc[3][ct], 0, 0, 0);
    }
  }

  const bool hb = (bias != nullptr);
  #pragma unroll
  for (int j = 0; j < 4; ++j) {
    int rb = rb0 + j;
    float4 cfs[4];
    if (hb) {
      #pragma unroll
      for (int reg = 0; reg < 4; ++reg) cfs[reg] = cntf[rb * 16 + q * 4 + reg];
    }
    #pragma unroll
    for (int ct = 0; ct < 8; ++ct) {
      int col = ct * 16 + l;
      float b0 = 0, b1 = 0, b2 = 0;
      if (hb) { b0 = bias[col]; b1 = bias[128 + col]; b2 = bias[256 + col]; }
      #pragma unroll
      for (int reg = 0; reg < 4; ++reg) {
        int t = rb * 16 + q * 4 + reg;
        float v = acc[j][ct][reg];
        if (hb) v += cfs[reg].x * b0 + cfs[reg].y * b1 + cfs[reg].z * b2;
        out[(size_t)t * 128 + col] = (bf16)fmaxf(v, 0.f);
      }
    }
  }
}

// ---------------- combines ----------------
__global__ __launch_bounds__(256) void combine1_kernel(
    const bf16* __restrict__ o0, const bf16* __restrict__ o1,
    const bf16* __restrict__ o2, const bf16* __restrict__ o3,
    const float* __restrict__ h, const int* __restrict__ spos,
    float* __restrict__ zbuf, u8* __restrict__ q8, bf16* __restrict__ Aq, int N)
{
  int g = blockIdx.x * 256 + threadIdx.x;
  if (g >= N * 16) return;
  int n = g >> 4, o = g & 15;
  int t = spos[n];
  size_t tb = (size_t)t * 16 + o;
  bf16x8 a0 = ((const bf16x8*)o0)[tb];
  bf16x8 a1 = ((const bf16x8*)o1)[tb];
  bf16x8 a2 = ((const bf16x8*)o2)[tb];
  bf16x8 a3 = ((const bf16x8*)o3)[tb];
  size_t nb = (size_t)n * 16 + o;
  float4 h0 = ((const float4*)h)[nb * 2];
  float4 h1 = ((const float4*)h)[nb * 2 + 1];
  float hv[8] = {h0.x, h0.y, h0.z, h0.w, h1.x, h1.y, h1.z, h1.w};
  float zv[8], qv[8];
  bf16x8 qb;
  #pragma unroll
  for (int j = 0; j < 8; ++j) {
    zv[j] = sigmoidf_((float)a0[j] + (float)a1[j]);
    qv[j] = sigmoidf_((float)a2[j] + (float)a3[j]) * hv[j];
    qb[j] = (bf16)qv[j];
  }
  ((float4*)zbuf)[nb * 2]     = make_float4(zv[0], zv[1], zv[2], zv[3]);
  ((float4*)zbuf)[nb * 2 + 1] = make_float4(zv[4], zv[5], zv[6], zv[7]);
  int lo = __builtin_amdgcn_cvt_pk_fp8_f32(qv[0], qv[1], 0, false);
  lo = __builtin_amdgcn_cvt_pk_fp8_f32(qv[2], qv[3], lo, true);
  int hi = __builtin_amdgcn_cvt_pk_fp8_f32(qv[4], qv[5], 0, false);
  hi = __builtin_amdgcn_cvt_pk_fp8_f32(qv[6], qv[7], hi, true);
  *(int2*)(q8 + (size_t)t * 128 + o * 8) = make_int2(lo, hi);
  size_t unit = (size_t)(t >> 4) * 1024 + (48 + o) * 16 + (t & 15);
  ((bf16x8*)Aq)[unit] = qb;
}

__global__ __launch_bounds__(256) void combine2_kernel(
    const float* __restrict__ zbuf, const bf16* __restrict__ o4, const bf16* __restrict__ o5,
    const float* __restrict__ h, const int* __restrict__ spos, float* __restrict__ out, int N)
{
  int g = blockIdx.x * 256 + threadIdx.x;
  if (g >= N * 16) return;
  int n = g >> 4, o = g & 15;
  int t = spos[n];
  size_t tb = (size_t)t * 16 + o;
  bf16x8 a = ((const bf16x8*)o4)[tb];
  bf16x8 b = ((const bf16x8*)o5)[tb];
  size_t nb = (size_t)n * 16 + o;
  float4 z0 = ((const float4*)zbuf)[nb * 2];
  float4 z1 = ((const float4*)zbuf)[nb * 2 + 1];
  float4 h0 = ((const float4*)h)[nb * 2];
  float4 h1 = ((const float4*)h)[nb * 2 + 1];
  float zv[8] = {z0.x, z0.y, z0.z, z0.w, z1.x, z1.y, z1.z, z1.w};
  float hv[8] = {h0.x, h0.y, h0.z, h0.w, h1.x, h1.y, h1.z, h1.w};
  float ov[8];
  #pragma unroll
  for (int j = 0; j < 8; ++j)
    ov[j] = zv[j] * hv[j] + (1.f - zv[j]) * tanhf((float)a[j] + (float)b[j]);
  ((float4*)out)[nb * 2]     = make_float4(ov[0], ov[1], ov[2], ov[3]);
  ((float4*)out)[nb * 2 + 1] = make_float4(ov[4], ov[5], ov[6], ov[7]);
}

// ---------------- host ----------------
extern "C" void kernel_launch(void* const* d_in, const int* in_sizes, int n_in,
                              void* d_out, int out_size, void* d_ws, size_t ws_size,
                              hipStream_t stream)
{
  (void)n_in; (void)out_size; (void)ws_size;
  const float* x    = (const float*)d_in[0];
  const float* h    = (const float*)d_in[1];
  const int*   ei   = (const int*)d_in[2];
  const int*   role = (const int*)d_in[3];
  const int N = in_sizes[0] / DH;
  const int E = in_sizes[2] / 2;
  const int Etot = E + N;
  const int rows_pad = ((N + 765) + 255) & ~255;
  const int gx = rows_pad / 256;
  const int n3 = N * 3;
  const int nb3 = (n3 + 1023) / 1024;

  // conv order: 0 xz, 1 hz, 2 xr, 3 hr, 4 xh, 5 hh
  static const int Wi[6]  = {4, 9, 13, 18, 22, 27};
  static const int Wgi[6] = {5, 10, 14, 19, 23, 28};
  static const int bgi[6] = {6, 11, 15, 20, 24, 29};
  static const int Si[6]  = {7, 12, 16, 21, 25, 30};

  char* p = (char*)d_ws;
  auto alloc = [&](size_t bytes) -> char* {
    char* r = p;
    p += (bytes + 255) & ~(size_t)255;
    return r;
  };

  bf16* Ax = (bf16*)alloc((size_t)rows_pad * 512 * 2);   // Aq aliases Ax
  bf16* Ah = (bf16*)alloc((size_t)rows_pad * 512 * 2);
  bf16* Aq = Ax;
  u8* xq8  = (u8*)alloc((size_t)rows_pad * 256);
  u8* q8   = (u8*)alloc((size_t)rows_pad * 128);
  bf16* outs[6];
  for (int c = 0; c < 5; ++c) outs[c] = (bf16*)alloc((size_t)rows_pad * 128 * 2);
  outs[5] = outs[0];
  float* zbuf = (float*)alloc((size_t)N * 128 * 4);
  float4* cntf = (float4*)alloc((size_t)rows_pad * 16);
  bf16* Wf = (bf16*)alloc((size_t)6 * 49152 * 2);
  bf16* Pf = (bf16*)alloc((size_t)18 * 16384 * 2);
  int* cnt3  = (int*)alloc((size_t)n3 * 4);
  int* off3  = (int*)alloc((size_t)(n3 + 1) * 4);
  int* fill3 = (int*)alloc((size_t)n3 * 4);
  int* bsum  = (int*)alloc((size_t)(nb3 + 1) * 4);
  int* ssrc  = (int*)alloc((size_t)Etot * 4);
  int* spos  = (int*)alloc((size_t)N * 4);
  int* sposinv = (int*)alloc((size_t)rows_pad * 4);
  int* rolecnt  = (int*)alloc(64);
  int* rolefill = (int*)alloc(64);
  int* roleinfo = (int*)alloc(64);

  hipMemsetAsync(cnt3, 0, (size_t)n3 * 4, stream);
  hipMemsetAsync(rolecnt, 0, 16, stream);
  hipMemsetAsync(sposinv, 0xFF, (size_t)rows_pad * 4, stream);   // -1 = pad row

  int egrid = (Etot + 255) / 256;
  int ngrid = (N + 255) / 256;
  hist_kernel<<<egrid, 256, 0, stream>>>(ei, role, cnt3, rolecnt, E, N);
  scan1_kernel<<<nb3, 1024, 0, stream>>>(cnt3, off3, bsum, n3);
  scan2_kernel<<<1, 64, 0, stream>>>(bsum, nb3, rolecnt, rolefill, roleinfo);
  scan3_kernel<<<nb3, 1024, 0, stream>>>(off3, fill3, bsum, n3);
  permscatter_kernel<<<ngrid, 256, 0, stream>>>(role, rolefill, spos, sposinv, N);
  scatter_kernel<<<egrid, 256, 0, stream>>>(ei, spos, roleinfo, fill3, ssrc, E, N);
  zeropad_kernel<<<384, 256, 0, stream>>>(roleinfo, Ax, Ah);

  prep_xh_kernel<<<(N * 32 + 255) / 256, 256, 0, stream>>>(x, h, spos, xq8, Ax, Ah, N);

  PrepW pw;
  for (int c = 0; c < 6; ++c) {
    pw.W[c] = (const float*)d_in[Wi[c]];
    pw.Wg[c] = (const float*)d_in[Wgi[c]];
    pw.bg[c] = (const float*)d_in[bgi[c]];
  }
  prep_wf_kernel<<<1152, 256, 0, stream>>>(pw, Wf);
  PrepP pp;
  for (int c = 0; c < 6; ++c) { pp.W[c] = (const float*)d_in[Wi[c]]; pp.S[c] = (const float*)d_in[Si[c]]; }
  prep_pf_kernel<<<2304, 128, 0, stream>>>(pp, Pf);

  gather_xh_kernel<<<rows_pad / 8, 512, 0, stream>>>(xq8, off3, ssrc, sposinv, Ax, Ah, cntf);

  // pass 1: one dispatch, cv 0..4 = {xz,xr,xh on Ax (bias)} + {hz,hr on Ah}
  GArgs g0;
  { int cvs[5] = {0, 2, 4, 1, 3};
    static const int bi2[5] = {8, 17, 26, -1, -1};
    const bf16* Apts[5] = {Ax, Ax, Ax, Ah, Ah};
    for (int k = 0; k < 5; ++k) {
      int c = cvs[k];
      g0.Ap[k] = Apts[k];
      g0.wf[k] = Wf + (size_t)c * 49152;
      g0.pf[k] = Pf + (size_t)c * 3 * 16384;
      g0.out[k] = outs[c];
      g0.bias[k] = (bi2[k] >= 0) ? (const float*)d_in[bi2[k]] : nullptr;
    } }
  gemm_kernel<<<dim3(gx, 5), 256, 0, stream>>>(g0, cntf, roleinfo);

  combine1_kernel<<<(N * 16 + 255) / 256, 256, 0, stream>>>(outs[0], outs[1], outs[2], outs[3],
                                                            h, spos, zbuf, q8, Aq, N);

  gather_q_kernel<<<rows_pad / 8, 512, 0, stream>>>(q8, off3, ssrc, sposinv, Aq);

  // pass 2: conv hh(5) on Aq
  GArgs g2 = {};
  g2.Ap[0] = Aq;
  g2.wf[0] = Wf + (size_t)5 * 49152;
  g2.pf[0] = Pf + (size_t)5 * 3 * 16384;
  g2.out[0] = outs[5];
  g2.bias[0] = nullptr;
  gemm_kernel<<<dim3(gx, 1), 256, 0, stream>>>(g2, cntf, roleinfo);

  combine2_kernel<<<(N * 16 + 255) / 256, 256, 0, stream>>>(zbuf, outs[4], outs[5], h, spos,
                                                            (float*)d_out, N);
}

// Round 4
// 704.173 us; speedup vs baseline: 1.0940x; 1.0367x over previous
//
#include <hip/hip_runtime.h>

// GraphGRU on MI355X — round 10.
//   scatter_kernel (115 µs, WRITE 110 MB from 6.6 MB payload = 16x line amplification)
//   replaced by two-pass bucketed scatter:
//     partition_kernel: edges -> (bin,t) records appended into dst-range buckets (b=dst>>8),
//       LDS histogram + bulk atomic alloc, ~168B contiguous runs. Bucket offsets come free
//       from off3 (bucket region = off3 range of its dst span).
//     binscatter_kernel: one WG per bucket replays records; ssrc writes confined to the
//       bucket's ~34KB slice from a single WG/XCD -> L2 merges, writeback = payload.
//   Everything else identical to round-9 (730 µs).

typedef __bf16 bf16;
typedef __bf16 bf16x8 __attribute__((ext_vector_type(8)));
typedef float  f32x4  __attribute__((ext_vector_type(4)));
typedef float  f32x2  __attribute__((ext_vector_type(2)));
typedef unsigned char u8;

#define DH 128

__device__ __forceinline__ float sigmoidf_(float x) { return 1.0f / (1.0f + expf(-x)); }

// ---------------- CSR build ----------------
__global__ __launch_bounds__(256) void hist_kernel(const int* __restrict__ ei, const int* __restrict__ role,
                                                   int* __restrict__ cnt3, int* __restrict__ rolecnt,
                                                   int E, int N)
{
  int i = blockIdx.x * 256 + threadIdx.x;
  int lane = threadIdx.x & 63;
  int r = (i < N) ? role[i] : -1;
  #pragma unroll
  for (int rr = 0; rr < 3; ++rr) {
    unsigned long long mask = __ballot(r == rr);
    if (lane == 0 && mask) atomicAdd(&rolecnt[rr], __popcll(mask));
  }
  if (i < E + N) {
    int src, dst;
    if (i < E) { src = ei[i]; dst = ei[E + i]; } else { src = i - E; dst = i - E; }
    int rs = (i < E) ? role[src] : r;
    if (i >= E) rs = role[i - E];
    atomicAdd(&cnt3[dst * 3 + rs], 1);
  }
}

__global__ __launch_bounds__(1024) void scan1_kernel(const int* __restrict__ cnt, int* __restrict__ off,
                                                     int* __restrict__ bsum, int n)
{
  __shared__ int wsum[16];
  int t = threadIdx.x, lane = t & 63, w = t >> 6;
  int idx = blockIdx.x * 1024 + t;
  int v = (idx < n) ? cnt[idx] : 0;
  int s = v;
  #pragma unroll
  for (int d = 1; d < 64; d <<= 1) { int u = __shfl_up(s, d); if (lane >= d) s += u; }
  if (lane == 63) wsum[w] = s;
  __syncthreads();
  if (w == 0 && lane < 16) {
    int ws = wsum[lane];
    #pragma unroll
    for (int d = 1; d < 16; d <<= 1) { int u = __shfl_up(ws, d); if (lane >= d) ws += u; }
    wsum[lane] = ws;
  }
  __syncthreads();
  int inc = ((w > 0) ? wsum[w - 1] : 0) + s;
  if (idx < n) off[idx + 1] = inc;
  if (t == 1023) bsum[blockIdx.x] = inc;
}

__global__ void scan2_kernel(int* __restrict__ bsum, int nb, const int* __restrict__ rolecnt,
                             int* __restrict__ rolefill, int* __restrict__ roleinfo)
{
  int lane = threadIdx.x;
  int carry = 0;
  for (int base = 0; base < nb; base += 64) {
    int v = (base + lane < nb) ? bsum[base + lane] : 0;
    int s = v;
    #pragma unroll
    for (int d = 1; d < 64; d <<= 1) { int u = __shfl_up(s, d); if (lane >= d) s += u; }
    if (base + lane < nb) bsum[base + lane] = carry + s - v;
    carry += __shfl(s, 63);
  }
  if (lane == 0) {
    int c0 = rolecnt[0], c1 = rolecnt[1], c2 = rolecnt[2];
    int s1 = (c0 + 255) & ~255;
    int s2 = s1 + ((c1 + 255) & ~255);
    int mp = s2 + ((c2 + 255) & ~255);
    rolefill[0] = 0; rolefill[1] = s1; rolefill[2] = s2;
    roleinfo[0] = s1; roleinfo[1] = s2;
    roleinfo[2] = c0;      roleinfo[3] = s1 - c0;
    roleinfo[4] = s1 + c1; roleinfo[5] = s2 - s1 - c1;
    roleinfo[6] = s2 + c2; roleinfo[7] = mp - s2 - c2;
  }
}

__global__ __launch_bounds__(1024) void scan3_kernel(int* __restrict__ off, int* __restrict__ fill,
                                                     const int* __restrict__ bsum, int n)
{
  int idx = blockIdx.x * 1024 + threadIdx.x;
  if (idx == 0) { off[0] = 0; fill[0] = 0; }
  if (idx < n) {
    int v = off[idx + 1] + bsum[blockIdx.x];
    off[idx + 1] = v;
    if (idx + 1 < n) fill[idx + 1] = v;
  }
}

// bucketfill[b] = off3[3 * min(b*W, N)]  (record-region start per dst-range bucket)
__global__ void bucketinit_kernel(const int* __restrict__ off3, int* __restrict__ bucketfill,
                                  int NB, int W, int N)
{
  int b = blockIdx.x * 256 + threadIdx.x;
  if (b < NB) {
    int d = min(b * W, N);
    bucketfill[b] = off3[d * 3];
  }
}

// stage 1: partition edges into dst-range buckets; records = (bin, t)
__global__ __launch_bounds__(256) void partition_kernel(
    const int* __restrict__ ei, const int* __restrict__ spos,
    const int* __restrict__ roleinfo, int* __restrict__ bucketfill,
    int2* __restrict__ recs, int E, int N, int shiftB)
{
  __shared__ int lcnt[256], lbase[256];
  const int base = blockIdx.x * 4096;
  const int s1 = roleinfo[0], s2 = roleinfo[1];
  lcnt[threadIdx.x] = 0;
  __syncthreads();
  int myb[16], mybin[16], myt[16];
  #pragma unroll
  for (int k = 0; k < 16; ++k) {
    int i = base + k * 256 + threadIdx.x;
    myb[k] = -1;
    if (i < E + N) {
      int src, dst;
      if (i < E) { src = ei[i]; dst = ei[E + i]; } else { src = i - E; dst = i - E; }
      int t = spos[src];
      int r = (t >= s2) ? 2 : (t >= s1) ? 1 : 0;
      myb[k] = dst >> shiftB;
      mybin[k] = dst * 3 + r;
      myt[k] = t;
      atomicAdd(&lcnt[myb[k]], 1);
    }
  }
  __syncthreads();
  int c = lcnt[threadIdx.x];
  lbase[threadIdx.x] = (c > 0) ? atomicAdd(&bucketfill[threadIdx.x], c) : 0;
  __syncthreads();
  lcnt[threadIdx.x] = 0;          // reuse as per-bucket cursor
  __syncthreads();
  #pragma unroll
  for (int k = 0; k < 16; ++k) {
    if (myb[k] >= 0) {
      int slot = atomicAdd(&lcnt[myb[k]], 1);
      recs[lbase[myb[k]] + slot] = make_int2(mybin[k], myt[k]);
    }
  }
}

// stage 2: replay one bucket per WG; ssrc writes confined to the bucket's slice
__global__ __launch_bounds__(1024) void binscatter_kernel(
    const int2* __restrict__ recs, const int* __restrict__ off3,
    int* __restrict__ fill3, int* __restrict__ ssrc, int W, int N)
{
  int b = blockIdx.x;
  int d0 = min(b * W, N), d1 = min((b + 1) * W, N);
  int s = off3[d0 * 3], e = off3[d1 * 3];
  for (int i = s + threadIdx.x; i < e; i += 1024) {
    int2 rec = recs[i];
    int pz = atomicAdd(&fill3[rec.x], 1);
    ssrc[pz] = rec.y;
  }
}

__global__ __launch_bounds__(256) void permscatter_kernel(const int* __restrict__ role, int* __restrict__ rolefill,
                                                          int* __restrict__ spos, int* __restrict__ sposinv, int N)
{
  int i = blockIdx.x * 256 + threadIdx.x;
  int lane = threadIdx.x & 63;
  int r = (i < N) ? role[i] : -1;
  #pragma unroll
  for (int rr = 0; rr < 3; ++rr) {
    unsigned long long mask = __ballot(r == rr);
    if (!mask) continue;
    int base = 0;
    if (lane == 0) base = atomicAdd(&rolefill[rr], __popcll(mask));
    base = __shfl(base, 0);
    if (r == rr) {
      int rank = (int)__popcll(mask & ((1ull << lane) - 1ull));
      int pos = base + rank;
      spos[i] = pos;
      sposinv[pos] = i;
    }
  }
}

__global__ __launch_bounds__(256) void zeropad_kernel(const int* __restrict__ roleinfo,
                                                      bf16* __restrict__ Ax, bf16* __restrict__ Ah)
{
  int id = blockIdx.x * 256 + threadIdx.x;   // 98304
  int a = id / 49152, rem = id % 49152;
  int gp = rem / 16384, r2 = rem % 16384;
  int rr = r2 >> 6, c = r2 & 63;
  int gs = roleinfo[2 + gp * 2], gl = roleinfo[3 + gp * 2];
  if (rr < gl) {
    int row = gs + rr;
    size_t unit = (size_t)(row >> 4) * 1024 + c * 16 + (row & 15);
    bf16x8 z = {};
    ((bf16x8*)(a == 0 ? Ax : Ah))[unit] = z;
  }
}

// ---------------- prep ----------------
__global__ __launch_bounds__(256) void prep_xh_kernel(const float* __restrict__ x, const float* __restrict__ h,
                                                      const int* __restrict__ spos, u8* __restrict__ xq8,
                                                      bf16* __restrict__ Ax, bf16* __restrict__ Ah, int N)
{
  int g = blockIdx.x * 256 + threadIdx.x;
  if (g >= N * 32) return;
  int n = g >> 5, j = g & 31;
  int t = spos[n];
  const float* src = (j < 16) ? (x + (size_t)n * 128 + (j << 3))
                              : (h + (size_t)n * 128 + ((j - 16) << 3));
  float4 v0 = ((const float4*)src)[0];
  float4 v1 = ((const float4*)src)[1];
  int lo = __builtin_amdgcn_cvt_pk_fp8_f32(v0.x, v0.y, 0, false);
  lo = __builtin_amdgcn_cvt_pk_fp8_f32(v0.z, v0.w, lo, true);
  int hi = __builtin_amdgcn_cvt_pk_fp8_f32(v1.x, v1.y, 0, false);
  hi = __builtin_amdgcn_cvt_pk_fp8_f32(v1.z, v1.w, hi, true);
  *(int2*)(xq8 + (size_t)t * 256 + j * 8) = make_int2(lo, hi);
  bf16x8 o;
  o[0] = (bf16)v0.x; o[1] = (bf16)v0.y; o[2] = (bf16)v0.z; o[3] = (bf16)v0.w;
  o[4] = (bf16)v1.x; o[5] = (bf16)v1.y; o[6] = (bf16)v1.z; o[7] = (bf16)v1.w;
  size_t unit = (size_t)(t >> 4) * 1024 + (48 + (j & 15)) * 16 + (t & 15);
  ((bf16x8*)(j < 16 ? Ax : Ah))[unit] = o;
}

struct PrepW { const float* W[6]; const float* Wg[6]; const float* bg[6]; };
__global__ __launch_bounds__(256) void prep_wf_kernel(PrepW pw, bf16* __restrict__ Wf)
{
  int idx = blockIdx.x * 256 + threadIdx.x;
  if (idx >= 294912) return;
  int cv = idx / 49152, pos = idx % 49152;
  int ks4q = pos >> 10;
  int col = (pos >> 3) & 127, j = pos & 7;
  int k = (ks4q >> 2) * 32 + (ks4q & 3) * 8 + j;
  int r = k >> 7, kk = k & 127;
  float g = sigmoidf_(pw.Wg[cv][r * 128 + col] + pw.bg[cv][r * 128 + col]);
  Wf[idx] = (bf16)(pw.W[cv][kk * 128 + col] * g);
}

struct PrepP { const float* W[6]; const float* S[6]; };
__global__ __launch_bounds__(128) void prep_pf_kernel(PrepP pp, bf16* __restrict__ Pf)
{
  int b = blockIdx.x;                          // 6*3*128
  int cv = b / 384, rem = b % 384;
  int r = rem >> 7, kp = rem & 127;
  int col = threadIdx.x;
  const float* W = pp.W[cv] + (size_t)kp * 128;
  const float* S = pp.S[cv] + (size_t)r * 16384;
  float sum = 0.f;
  #pragma unroll 4
  for (int j2 = 0; j2 < 128; ++j2) sum += W[j2] * S[j2 * 128 + col];
  size_t o = (size_t)(cv * 3 + r) * 16384 + ((size_t)(kp >> 3) * 128 + col) * 8 + (kp & 7);
  Pf[o] = (bf16)sum;
}

// ---------------- gathers (t-ordered 8-node blocks, cooperative full-line NT writes) ----------------
#define ACCUM16(U, d) do { f32x2 f_;                                                   \
  f_ = __builtin_amdgcn_cvt_pk_f32_fp8((d).x, false); U[0]  += f_[0]; U[1]  += f_[1];  \
  f_ = __builtin_amdgcn_cvt_pk_f32_fp8((d).x, true);  U[2]  += f_[0]; U[3]  += f_[1];  \
  f_ = __builtin_amdgcn_cvt_pk_f32_fp8((d).y, false); U[4]  += f_[0]; U[5]  += f_[1];  \
  f_ = __builtin_amdgcn_cvt_pk_f32_fp8((d).y, true);  U[6]  += f_[0]; U[7]  += f_[1];  \
  f_ = __builtin_amdgcn_cvt_pk_f32_fp8((d).z, false); U[8]  += f_[0]; U[9]  += f_[1];  \
  f_ = __builtin_amdgcn_cvt_pk_f32_fp8((d).z, true);  U[10] += f_[0]; U[11] += f_[1];  \
  f_ = __builtin_amdgcn_cvt_pk_f32_fp8((d).w, false); U[12] += f_[0]; U[13] += f_[1];  \
  f_ = __builtin_amdgcn_cvt_pk_f32_fp8((d).w, true);  U[14] += f_[0]; U[15] += f_[1];  \
} while (0)

#define ACCSEL16(d, p) do {                      \
  if ((p) < o1)      { ACCUM16(u0, d); }         \
  else if ((p) < o2) { ACCUM16(u1, d); }         \
  else               { ACCUM16(u2, d); }         \
} while (0)

__global__ __launch_bounds__(512) void gather_xh_kernel(
    const u8* __restrict__ xq8, const int* __restrict__ off3, const int* __restrict__ ssrc,
    const int* __restrict__ sposinv, bf16* __restrict__ Ax, bf16* __restrict__ Ah,
    float4* __restrict__ cntf)
{
  __shared__ alignas(16) bf16 lds[8][768];
  int w = threadIdx.x >> 6, lane = threadIdx.x & 63;
  int t0 = blockIdx.x * 8;
  int t = t0 + w;
  int node = sposinv[t];                 // -1 for pad rows
  int qt = lane >> 4, ql = lane & 15;

  if (node >= 0) {
    int o0 = __builtin_amdgcn_readfirstlane(off3[node * 3]);
    int o1 = __builtin_amdgcn_readfirstlane(off3[node * 3 + 1]);
    int o2 = __builtin_amdgcn_readfirstlane(off3[node * 3 + 2]);
    int o3 = __builtin_amdgcn_readfirstlane(off3[node * 3 + 3]);
    float inv = 1.0f / (float)(o3 - o0);
    const u8* base = xq8 + ql * 16;

    float u0[16], u1[16], u2[16];
    #pragma unroll
    for (int k = 0; k < 16; ++k) { u0[k] = 0.f; u1[k] = 0.f; u2[k] = 0.f; }

    const int e = o3, emax = o3 - 1;
    for (int i = o0; i < e; i += 16) {
      int p0 = i + qt, p1 = p0 + 4, p2 = p0 + 8, p3 = p0 + 12;
      int t0i = ssrc[min(p0, emax)];
      int t1i = ssrc[min(p1, emax)];
      int t2i = ssrc[min(p2, emax)];
      int t3i = ssrc[min(p3, emax)];
      int4 d0 = make_int4(0, 0, 0, 0), d1 = d0, d2 = d0, d3 = d0;
      if (p0 < e) d0 = *(const int4*)(base + (size_t)t0i * 256);
      if (p1 < e) d1 = *(const int4*)(base + (size_t)t1i * 256);
      if (p2 < e) d2 = *(const int4*)(base + (size_t)t2i * 256);
      if (p3 < e) d3 = *(const int4*)(base + (size_t)t3i * 256);
      ACCSEL16(d0, p0);
      ACCSEL16(d1, p1);
      ACCSEL16(d2, p2);
      ACCSEL16(d3, p3);
    }

    #pragma unroll
    for (int k = 0; k < 16; ++k) {
      u0[k] += __shfl_xor(u0[k], 16); u0[k] += __shfl_xor(u0[k], 32);
      u1[k] += __shfl_xor(u1[k], 16); u1[k] += __shfl_xor(u1[k], 32);
      u2[k] += __shfl_xor(u2[k], 16); u2[k] += __shfl_xor(u2[k], 32);
    }
    if (qt == 0) {
      bf16x8 p0v, p1v;
      int sb0 = (ql < 8) ? (ql * 16) : (384 + (ql - 8) * 16);
      #pragma unroll
      for (int k = 0; k < 8; ++k) { p0v[k] = (bf16)(u0[k] * inv); p1v[k] = (bf16)(u0[8 + k] * inv); }
      *(bf16x8*)&lds[w][sb0] = p0v;
      *(bf16x8*)&lds[w][sb0 + 8] = p1v;
      #pragma unroll
      for (int k = 0; k < 8; ++k) { p0v[k] = (bf16)(u1[k] * inv); p1v[k] = (bf16)(u1[8 + k] * inv); }
      *(bf16x8*)&lds[w][sb0 + 128] = p0v;
      *(bf16x8*)&lds[w][sb0 + 136] = p1v;
      #pragma unroll
      for (int k = 0; k < 8; ++k) { p0v[k] = (bf16)(u2[k] * inv); p1v[k] = (bf16)(u2[8 + k] * inv); }
      *(bf16x8*)&lds[w][sb0 + 256] = p0v;
      *(bf16x8*)&lds[w][sb0 + 264] = p1v;
    }
    if (lane == 0)
      cntf[t] = make_float4((o1 - o0) * inv, (o2 - o1) * inv, (o3 - o2) * inv, (float)(o3 - o0));
  } else {
    // pad row: zero-fill this wave's LDS section so the cooperative write stores zeros
    if (lane < 48) {
      bf16x8 z = {};
      *(bf16x8*)&lds[w][lane * 16] = z;
      *(bf16x8*)&lds[w][lane * 16 + 8] = z;
    }
    if (lane == 0) cntf[t] = make_float4(0.f, 0.f, 0.f, 0.f);
  }

  __syncthreads();

  // cooperative write: 8 consecutive rows (t0..t0+7, same 16-group) -> full 128-B lines
  int tid = threadIdx.x;
  if (tid < 384) {
    int lc = tid >> 3, row = tid & 7;
    size_t unit = (size_t)(t0 >> 4) * 1024 + lc * 16 + (t0 & 15) + row;
    __builtin_nontemporal_store(*(const bf16x8*)&lds[row][lc * 8], (bf16x8*)Ax + unit);
    __builtin_nontemporal_store(*(const bf16x8*)&lds[row][384 + lc * 8], (bf16x8*)Ah + unit);
  }
}

#define ACCUM8(U, d) do { f32x2 f_;                                                  \
  f_ = __builtin_amdgcn_cvt_pk_f32_fp8((d).x, false); U[0] += f_[0]; U[1] += f_[1];  \
  f_ = __builtin_amdgcn_cvt_pk_f32_fp8((d).x, true);  U[2] += f_[0]; U[3] += f_[1];  \
  f_ = __builtin_amdgcn_cvt_pk_f32_fp8((d).y, false); U[4] += f_[0]; U[5] += f_[1];  \
  f_ = __builtin_amdgcn_cvt_pk_f32_fp8((d).y, true);  U[6] += f_[0]; U[7] += f_[1];  \
} while (0)

#define ACCSEL8(d, p) do {                      \
  if ((p) < o1)      { ACCUM8(v0, d); }         \
  else if ((p) < o2) { ACCUM8(v1, d); }         \
  else               { ACCUM8(v2, d); }         \
} while (0)

__global__ __launch_bounds__(512) void gather_q_kernel(
    const u8* __restrict__ q8, const int* __restrict__ off3, const int* __restrict__ ssrc,
    const int* __restrict__ sposinv, bf16* __restrict__ Aq)
{
  __shared__ alignas(16) bf16 lds[8][384];
  int w = threadIdx.x >> 6, lane = threadIdx.x & 63;
  int t0 = blockIdx.x * 8;
  int t = t0 + w;
  int node = sposinv[t];
  int qt = lane >> 4, ql = lane & 15;

  if (node >= 0) {
    int o0 = __builtin_amdgcn_readfirstlane(off3[node * 3]);
    int o1 = __builtin_amdgcn_readfirstlane(off3[node * 3 + 1]);
    int o2 = __builtin_amdgcn_readfirstlane(off3[node * 3 + 2]);
    int o3 = __builtin_amdgcn_readfirstlane(off3[node * 3 + 3]);
    float inv = 1.0f / (float)(o3 - o0);
    const u8* base = q8 + ql * 8;

    float v0[8], v1[8], v2[8];
    #pragma unroll
    for (int k = 0; k < 8; ++k) { v0[k] = 0.f; v1[k] = 0.f; v2[k] = 0.f; }

    const int e = o3, emax = o3 - 1;
    for (int i = o0; i < e; i += 16) {
      int p0 = i + qt, p1 = p0 + 4, p2 = p0 + 8, p3 = p0 + 12;
      int t0i = ssrc[min(p0, emax)];
      int t1i = ssrc[min(p1, emax)];
      int t2i = ssrc[min(p2, emax)];
      int t3i = ssrc[min(p3, emax)];
      int2 d0 = make_int2(0, 0), d1 = d0, d2 = d0, d3 = d0;
      if (p0 < e) d0 = *(const int2*)(base + (size_t)t0i * 128);
      if (p1 < e) d1 = *(const int2*)(base + (size_t)t1i * 128);
      if (p2 < e) d2 = *(const int2*)(base + (size_t)t2i * 128);
      if (p3 < e) d3 = *(const int2*)(base + (size_t)t3i * 128);
      ACCSEL8(d0, p0);
      ACCSEL8(d1, p1);
      ACCSEL8(d2, p2);
      ACCSEL8(d3, p3);
    }

    #pragma unroll
    for (int k = 0; k < 8; ++k) {
      v0[k] += __shfl_xor(v0[k], 16); v0[k] += __shfl_xor(v0[k], 32);
      v1[k] += __shfl_xor(v1[k], 16); v1[k] += __shfl_xor(v1[k], 32);
      v2[k] += __shfl_xor(v2[k], 16); v2[k] += __shfl_xor(v2[k], 32);
    }
    if (qt == 0) {
      bf16x8 pk;
      #pragma unroll
      for (int k = 0; k < 8; ++k) pk[k] = (bf16)(v0[k] * inv);
      *(bf16x8*)&lds[w][ql * 8] = pk;
      #pragma unroll
      for (int k = 0; k < 8; ++k) pk[k] = (bf16)(v1[k] * inv);
      *(bf16x8*)&lds[w][128 + ql * 8] = pk;
      #pragma unroll
      for (int k = 0; k < 8; ++k) pk[k] = (bf16)(v2[k] * inv);
      *(bf16x8*)&lds[w][256 + ql * 8] = pk;
    }
  } else {
    if (lane < 48) {
      bf16x8 z = {};
      *(bf16x8*)&lds[w][lane * 8] = z;
    }
  }

  __syncthreads();

  int tid = threadIdx.x;
  if (tid < 384) {
    int lc = tid >> 3, row = tid & 7;
    size_t unit = (size_t)(t0 >> 4) * 1024 + lc * 16 + (t0 & 15) + row;
    __builtin_nontemporal_store(*(const bf16x8*)&lds[row][lc * 8], (bf16x8*)Aq + unit);
  }
}

// ---------------- streaming MFMA GEMM (no LDS/barriers; 4 row-blocks per wave) ----------------
struct GArgs {
  const bf16* Ap[5];
  const bf16* wf[5];
  const bf16* pf[5];
  bf16* out[5];
  const float* bias[5];
};

__global__ __launch_bounds__(256) void gemm_kernel(GArgs ga, const float4* __restrict__ cntf,
                                                   const int* __restrict__ roleinfo)
{
  const int cv = blockIdx.y;
  const bf16* __restrict__ Ap = ga.Ap[cv];
  const bf16* __restrict__ wf = ga.wf[cv];
  const bf16* __restrict__ pf = ga.pf[cv];
  bf16* __restrict__ out = ga.out[cv];
  const float* __restrict__ bias = ga.bias[cv];

  const int w = threadIdx.x >> 6, lane = threadIdx.x & 63;
  const int q = lane >> 4, l = lane & 15;
  const int rb0 = blockIdx.x * 16 + w * 4;
  const int row0 = blockIdx.x * 256;
  const int s1 = roleinfo[0], s2 = roleinfo[1];
  const int role = (row0 >= s2) ? 2 : (row0 >= s1) ? 1 : 0;
  const int laneoff = q * 128 + l;

  f32x4 acc[4][8];
  #pragma unroll
  for (int j = 0; j < 4; ++j)
    #pragma unroll
    for (int ct = 0; ct < 8; ++ct)
      #pragma unroll
      for (int k = 0; k < 4; ++k) acc[j][ct][k] = 0.f;

  const bf16x8* A0 = (const bf16x8*)Ap + (size_t)rb0 * 1024 + lane;
  const bf16x8* WF = (const bf16x8*)wf + laneoff;
  const bf16x8* PF = (const bf16x8*)pf + role * 2048 + laneoff;

  #pragma unroll 2
  for (int ks = 0; ks < 16; ++ks) {
    const bf16x8* bp = (ks < 12) ? (WF + ks * 512) : (PF + (ks - 12) * 512);
    bf16x8 a0 = A0[ks * 64];
    bf16x8 a1 = A0[1024 + ks * 64];
    bf16x8 a2 = A0[2048 + ks * 64];
    bf16x8 a3 = A0[3072 + ks * 64];
    #pragma unroll
    for (int ct = 0; ct < 8; ++ct) {
      bf16x8 b = bp[ct * 16];
      acc[0][ct] = __builtin_amdgcn_mfma_f32_16x16x32_bf16(a0, b, acc[0][ct], 0, 0, 0);
      acc[1][ct] = __builtin_amdgcn_mfma_f32_16x16x32_bf16(a1, b, acc[1][ct], 0, 0, 0);
      acc[2][ct] = __builtin_amdgcn_mfma_f32_16x16x32_bf16(a2, b, acc[2][ct], 0, 0, 0);
      acc[3][ct] = __builtin_amdgcn_mfma_f32_16x16x32_bf16(a3, b, acc[3][ct], 0, 0, 0);
    }
  }

  const bool hb = (bias != nullptr);
  #pragma unroll
  for (int j = 0; j < 4; ++j) {
    int rb = rb0 + j;
    float4 cfs[4];
    if (hb) {
      #pragma unroll
      for (int reg = 0; reg < 4; ++reg) cfs[reg] = cntf[rb * 16 + q * 4 + reg];
    }
    #pragma unroll
    for (int ct = 0; ct < 8; ++ct) {
      int col = ct * 16 + l;
      float b0 = 0, b1 = 0, b2 = 0;
      if (hb) { b0 = bias[col]; b1 = bias[128 + col]; b2 = bias[256 + col]; }
      #pragma unroll
      for (int reg = 0; reg < 4; ++reg) {
        int t = rb * 16 + q * 4 + reg;
        float v = acc[j][ct][reg];
        if (hb) v += cfs[reg].x * b0 + cfs[reg].y * b1 + cfs[reg].z * b2;
        out[(size_t)t * 128 + col] = (bf16)fmaxf(v, 0.f);
      }
    }
  }
}

// ---------------- combines ----------------
__global__ __launch_bounds__(256) void combine1_kernel(
    const bf16* __restrict__ o0, const bf16* __restrict__ o1,
    const bf16* __restrict__ o2, const bf16* __restrict__ o3,
    const float* __restrict__ h, const int* __restrict__ spos,
    float* __restrict__ zbuf, u8* __restrict__ q8, bf16* __restrict__ Aq, int N)
{
  int g = blockIdx.x * 256 + threadIdx.x;
  if (g >= N * 16) return;
  int n = g >> 4, o = g & 15;
  int t = spos[n];
  size_t tb = (size_t)t * 16 + o;
  bf16x8 a0 = ((const bf16x8*)o0)[tb];
  bf16x8 a1 = ((const bf16x8*)o1)[tb];
  bf16x8 a2 = ((const bf16x8*)o2)[tb];
  bf16x8 a3 = ((const bf16x8*)o3)[tb];
  size_t nb = (size_t)n * 16 + o;
  float4 h0 = ((const float4*)h)[nb * 2];
  float4 h1 = ((const float4*)h)[nb * 2 + 1];
  float hv[8] = {h0.x, h0.y, h0.z, h0.w, h1.x, h1.y, h1.z, h1.w};
  float zv[8], qv[8];
  bf16x8 qb;
  #pragma unroll
  for (int j = 0; j < 8; ++j) {
    zv[j] = sigmoidf_((float)a0[j] + (float)a1[j]);
    qv[j] = sigmoidf_((float)a2[j] + (float)a3[j]) * hv[j];
    qb[j] = (bf16)qv[j];
  }
  ((float4*)zbuf)[nb * 2]     = make_float4(zv[0], zv[1], zv[2], zv[3]);
  ((float4*)zbuf)[nb * 2 + 1] = make_float4(zv[4], zv[5], zv[6], zv[7]);
  int lo = __builtin_amdgcn_cvt_pk_fp8_f32(qv[0], qv[1], 0, false);
  lo = __builtin_amdgcn_cvt_pk_fp8_f32(qv[2], qv[3], lo, true);
  int hi = __builtin_amdgcn_cvt_pk_fp8_f32(qv[4], qv[5], 0, false);
  hi = __builtin_amdgcn_cvt_pk_fp8_f32(qv[6], qv[7], hi, true);
  *(int2*)(q8 + (size_t)t * 128 + o * 8) = make_int2(lo, hi);
  size_t unit = (size_t)(t >> 4) * 1024 + (48 + o) * 16 + (t & 15);
  ((bf16x8*)Aq)[unit] = qb;
}

__global__ __launch_bounds__(256) void combine2_kernel(
    const float* __restrict__ zbuf, const bf16* __restrict__ o4, const bf16* __restrict__ o5,
    const float* __restrict__ h, const int* __restrict__ spos, float* __restrict__ out, int N)
{
  int g = blockIdx.x * 256 + threadIdx.x;
  if (g >= N * 16) return;
  int n = g >> 4, o = g & 15;
  int t = spos[n];
  size_t tb = (size_t)t * 16 + o;
  bf16x8 a = ((const bf16x8*)o4)[tb];
  bf16x8 b = ((const bf16x8*)o5)[tb];
  size_t nb = (size_t)n * 16 + o;
  float4 z0 = ((const float4*)zbuf)[nb * 2];
  float4 z1 = ((const float4*)zbuf)[nb * 2 + 1];
  float4 h0 = ((const float4*)h)[nb * 2];
  float4 h1 = ((const float4*)h)[nb * 2 + 1];
  float zv[8] = {z0.x, z0.y, z0.z, z0.w, z1.x, z1.y, z1.z, z1.w};
  float hv[8] = {h0.x, h0.y, h0.z, h0.w, h1.x, h1.y, h1.z, h1.w};
  float ov[8];
  #pragma unroll
  for (int j = 0; j < 8; ++j)
    ov[j] = zv[j] * hv[j] + (1.f - zv[j]) * tanhf((float)a[j] + (float)b[j]);
  ((float4*)out)[nb * 2]     = make_float4(ov[0], ov[1], ov[2], ov[3]);
  ((float4*)out)[nb * 2 + 1] = make_float4(ov[4], ov[5], ov[6], ov[7]);
}

// ---------------- host ----------------
extern "C" void kernel_launch(void* const* d_in, const int* in_sizes, int n_in,
                              void* d_out, int out_size, void* d_ws, size_t ws_size,
                              hipStream_t stream)
{
  (void)n_in; (void)out_size; (void)ws_size;
  const float* x    = (const float*)d_in[0];
  const float* h    = (const float*)d_in[1];
  const int*   ei   = (const int*)d_in[2];
  const int*   role = (const int*)d_in[3];
  const int N = in_sizes[0] / DH;
  const int E = in_sizes[2] / 2;
  const int Etot = E + N;
  const int rows_pad = ((N + 765) + 255) & ~255;
  const int gx = rows_pad / 256;
  const int n3 = N * 3;
  const int nb3 = (n3 + 1023) / 1024;

  // bucket geometry: <=256 buckets of W=2^shiftB dst rows
  int shiftB = 8;
  while (((N - 1) >> shiftB) >= 256) ++shiftB;
  const int W = 1 << shiftB;
  const int NB = (N + W - 1) >> shiftB;

  // conv order: 0 xz, 1 hz, 2 xr, 3 hr, 4 xh, 5 hh
  static const int Wi[6]  = {4, 9, 13, 18, 22, 27};
  static const int Wgi[6] = {5, 10, 14, 19, 23, 28};
  static const int bgi[6] = {6, 11, 15, 20, 24, 29};
  static const int Si[6]  = {7, 12, 16, 21, 25, 30};

  char* p = (char*)d_ws;
  auto alloc = [&](size_t bytes) -> char* {
    char* r = p;
    p += (bytes + 255) & ~(size_t)255;
    return r;
  };

  bf16* Ax = (bf16*)alloc((size_t)rows_pad * 512 * 2);   // Aq aliases Ax
  bf16* Ah = (bf16*)alloc((size_t)rows_pad * 512 * 2);
  bf16* Aq = Ax;
  u8* xq8  = (u8*)alloc((size_t)rows_pad * 256);
  u8* q8   = (u8*)alloc((size_t)rows_pad * 128);
  bf16* outs[6];
  for (int c = 0; c < 5; ++c) outs[c] = (bf16*)alloc((size_t)rows_pad * 128 * 2);
  outs[5] = outs[0];
  float* zbuf = (float*)alloc((size_t)N * 128 * 4);
  float4* cntf = (float4*)alloc((size_t)rows_pad * 16);
  bf16* Wf = (bf16*)alloc((size_t)6 * 49152 * 2);
  bf16* Pf = (bf16*)alloc((size_t)18 * 16384 * 2);
  int* cnt3  = (int*)alloc((size_t)n3 * 4);
  int* off3  = (int*)alloc((size_t)(n3 + 1) * 4);
  int* fill3 = (int*)alloc((size_t)n3 * 4);
  int* bsum  = (int*)alloc((size_t)(nb3 + 1) * 4);
  int* ssrc  = (int*)alloc((size_t)Etot * 4);
  int2* recs = (int2*)alloc((size_t)Etot * 8);
  int* spos  = (int*)alloc((size_t)N * 4);
  int* sposinv = (int*)alloc((size_t)rows_pad * 4);
  int* rolecnt  = (int*)alloc(64);
  int* rolefill = (int*)alloc(64);
  int* roleinfo = (int*)alloc(64);
  int* bucketfill = (int*)alloc((size_t)(NB + 1) * 4);

  hipMemsetAsync(cnt3, 0, (size_t)n3 * 4, stream);
  hipMemsetAsync(rolecnt, 0, 16, stream);
  hipMemsetAsync(sposinv, 0xFF, (size_t)rows_pad * 4, stream);   // -1 = pad row

  int egrid = (Etot + 255) / 256;
  int ngrid = (N + 255) / 256;
  hist_kernel<<<egrid, 256, 0, stream>>>(ei, role, cnt3, rolecnt, E, N);
  scan1_kernel<<<nb3, 1024, 0, stream>>>(cnt3, off3, bsum, n3);
  scan2_kernel<<<1, 64, 0, stream>>>(bsum, nb3, rolecnt, rolefill, roleinfo);
  scan3_kernel<<<nb3, 1024, 0, stream>>>(off3, fill3, bsum, n3);
  permscatter_kernel<<<ngrid, 256, 0, stream>>>(role, rolefill, spos, sposinv, N);
  bucketinit_kernel<<<1, 256, 0, stream>>>(off3, bucketfill, NB, W, N);
  partition_kernel<<<(Etot + 4095) / 4096, 256, 0, stream>>>(ei, spos, roleinfo, bucketfill,
                                                             recs, E, N, shiftB);
  binscatter_kernel<<<NB, 1024, 0, stream>>>(recs, off3, fill3, ssrc, W, N);
  zeropad_kernel<<<384, 256, 0, stream>>>(roleinfo, Ax, Ah);

  prep_xh_kernel<<<(N * 32 + 255) / 256, 256, 0, stream>>>(x, h, spos, xq8, Ax, Ah, N);

  PrepW pw;
  for (int c = 0; c < 6; ++c) {
    pw.W[c] = (const float*)d_in[Wi[c]];
    pw.Wg[c] = (const float*)d_in[Wgi[c]];
    pw.bg[c] = (const float*)d_in[bgi[c]];
  }
  prep_wf_kernel<<<1152, 256, 0, stream>>>(pw, Wf);
  PrepP pp;
  for (int c = 0; c < 6; ++c) { pp.W[c] = (const float*)d_in[Wi[c]]; pp.S[c] = (const float*)d_in[Si[c]]; }
  prep_pf_kernel<<<2304, 128, 0, stream>>>(pp, Pf);

  gather_xh_kernel<<<rows_pad / 8, 512, 0, stream>>>(xq8, off3, ssrc, sposinv, Ax, Ah, cntf);

  // pass 1: one dispatch, cv 0..4 = {xz,xr,xh on Ax (bias)} + {hz,hr on Ah}
  GArgs g0;
  { int cvs[5] = {0, 2, 4, 1, 3};
    static const int bi2[5] = {8, 17, 26, -1, -1};
    const bf16* Apts[5] = {Ax, Ax, Ax, Ah, Ah};
    for (int k = 0; k < 5; ++k) {
      int c = cvs[k];
      g0.Ap[k] = Apts[k];
      g0.wf[k] = Wf + (size_t)c * 49152;
      g0.pf[k] = Pf + (size_t)c * 3 * 16384;
      g0.out[k] = outs[c];
      g0.bias[k] = (bi2[k] >= 0) ? (const float*)d_in[bi2[k]] : nullptr;
    } }
  gemm_kernel<<<dim3(gx, 5), 256, 0, stream>>>(g0, cntf, roleinfo);

  combine1_kernel<<<(N * 16 + 255) / 256, 256, 0, stream>>>(outs[0], outs[1], outs[2], outs[3],
                                                            h, spos, zbuf, q8, Aq, N);

  gather_q_kernel<<<rows_pad / 8, 512, 0, stream>>>(q8, off3, ssrc, sposinv, Aq);

  // pass 2: conv hh(5) on Aq
  GArgs g2 = {};
  g2.Ap[0] = Aq;
  g2.wf[0] = Wf + (size_t)5 * 49152;
  g2.pf[0] = Pf + (size_t)5 * 3 * 16384;
  g2.out[0] = outs[5];
  g2.bias[0] = nullptr;
  gemm_kernel<<<dim3(gx, 1), 256, 0, stream>>>(g2, cntf, roleinfo);

  combine2_kernel<<<(N * 16 + 255) / 256, 256, 0, stream>>>(zbuf, outs[4], outs[5], h, spos,
                                                            (float*)d_out, N);
}

// Round 5
// 682.257 us; speedup vs baseline: 1.1291x; 1.0321x over previous
//
#include <hip/hip_runtime.h>

// GraphGRU on MI355X — round 11.
//   gemm_kernel was 1-wave/SIMD (acc[4][8]=128 AGPR + 152 VGPR ~ 280/512 regs) ->
//   latency-bound at MfmaUtil 11.8%. Halved per-wave tile to 2 row-blocks (acc[2][8]=64),
//   doubled grid (gx=rows_pad/128), __launch_bounds__(256,3) for 3 waves/SIMD.
//   B re-reads double but Wf/Pf are L2-resident. Everything else identical to round-10 (704 µs).

typedef __bf16 bf16;
typedef __bf16 bf16x8 __attribute__((ext_vector_type(8)));
typedef float  f32x4  __attribute__((ext_vector_type(4)));
typedef float  f32x2  __attribute__((ext_vector_type(2)));
typedef unsigned char u8;

#define DH 128

__device__ __forceinline__ float sigmoidf_(float x) { return 1.0f / (1.0f + expf(-x)); }

// ---------------- CSR build ----------------
__global__ __launch_bounds__(256) void hist_kernel(const int* __restrict__ ei, const int* __restrict__ role,
                                                   int* __restrict__ cnt3, int* __restrict__ rolecnt,
                                                   int E, int N)
{
  int i = blockIdx.x * 256 + threadIdx.x;
  int lane = threadIdx.x & 63;
  int r = (i < N) ? role[i] : -1;
  #pragma unroll
  for (int rr = 0; rr < 3; ++rr) {
    unsigned long long mask = __ballot(r == rr);
    if (lane == 0 && mask) atomicAdd(&rolecnt[rr], __popcll(mask));
  }
  if (i < E + N) {
    int src, dst;
    if (i < E) { src = ei[i]; dst = ei[E + i]; } else { src = i - E; dst = i - E; }
    int rs = (i < E) ? role[src] : r;
    if (i >= E) rs = role[i - E];
    atomicAdd(&cnt3[dst * 3 + rs], 1);
  }
}

__global__ __launch_bounds__(1024) void scan1_kernel(const int* __restrict__ cnt, int* __restrict__ off,
                                                     int* __restrict__ bsum, int n)
{
  __shared__ int wsum[16];
  int t = threadIdx.x, lane = t & 63, w = t >> 6;
  int idx = blockIdx.x * 1024 + t;
  int v = (idx < n) ? cnt[idx] : 0;
  int s = v;
  #pragma unroll
  for (int d = 1; d < 64; d <<= 1) { int u = __shfl_up(s, d); if (lane >= d) s += u; }
  if (lane == 63) wsum[w] = s;
  __syncthreads();
  if (w == 0 && lane < 16) {
    int ws = wsum[lane];
    #pragma unroll
    for (int d = 1; d < 16; d <<= 1) { int u = __shfl_up(ws, d); if (lane >= d) ws += u; }
    wsum[lane] = ws;
  }
  __syncthreads();
  int inc = ((w > 0) ? wsum[w - 1] : 0) + s;
  if (idx < n) off[idx + 1] = inc;
  if (t == 1023) bsum[blockIdx.x] = inc;
}

__global__ void scan2_kernel(int* __restrict__ bsum, int nb, const int* __restrict__ rolecnt,
                             int* __restrict__ rolefill, int* __restrict__ roleinfo)
{
  int lane = threadIdx.x;
  int carry = 0;
  for (int base = 0; base < nb; base += 64) {
    int v = (base + lane < nb) ? bsum[base + lane] : 0;
    int s = v;
    #pragma unroll
    for (int d = 1; d < 64; d <<= 1) { int u = __shfl_up(s, d); if (lane >= d) s += u; }
    if (base + lane < nb) bsum[base + lane] = carry + s - v;
    carry += __shfl(s, 63);
  }
  if (lane == 0) {
    int c0 = rolecnt[0], c1 = rolecnt[1], c2 = rolecnt[2];
    int s1 = (c0 + 255) & ~255;
    int s2 = s1 + ((c1 + 255) & ~255);
    int mp = s2 + ((c2 + 255) & ~255);
    rolefill[0] = 0; rolefill[1] = s1; rolefill[2] = s2;
    roleinfo[0] = s1; roleinfo[1] = s2;
    roleinfo[2] = c0;      roleinfo[3] = s1 - c0;
    roleinfo[4] = s1 + c1; roleinfo[5] = s2 - s1 - c1;
    roleinfo[6] = s2 + c2; roleinfo[7] = mp - s2 - c2;
  }
}

__global__ __launch_bounds__(1024) void scan3_kernel(int* __restrict__ off, int* __restrict__ fill,
                                                     const int* __restrict__ bsum, int n)
{
  int idx = blockIdx.x * 1024 + threadIdx.x;
  if (idx == 0) { off[0] = 0; fill[0] = 0; }
  if (idx < n) {
    int v = off[idx + 1] + bsum[blockIdx.x];
    off[idx + 1] = v;
    if (idx + 1 < n) fill[idx + 1] = v;
  }
}

// bucketfill[b] = off3[3 * min(b*W, N)]  (record-region start per dst-range bucket)
__global__ void bucketinit_kernel(const int* __restrict__ off3, int* __restrict__ bucketfill,
                                  int NB, int W, int N)
{
  int b = blockIdx.x * 256 + threadIdx.x;
  if (b < NB) {
    int d = min(b * W, N);
    bucketfill[b] = off3[d * 3];
  }
}

// stage 1: partition edges into dst-range buckets; records = (bin, t)
__global__ __launch_bounds__(256) void partition_kernel(
    const int* __restrict__ ei, const int* __restrict__ spos,
    const int* __restrict__ roleinfo, int* __restrict__ bucketfill,
    int2* __restrict__ recs, int E, int N, int shiftB)
{
  __shared__ int lcnt[256], lbase[256];
  const int base = blockIdx.x * 4096;
  const int s1 = roleinfo[0], s2 = roleinfo[1];
  lcnt[threadIdx.x] = 0;
  __syncthreads();
  int myb[16], mybin[16], myt[16];
  #pragma unroll
  for (int k = 0; k < 16; ++k) {
    int i = base + k * 256 + threadIdx.x;
    myb[k] = -1;
    if (i < E + N) {
      int src, dst;
      if (i < E) { src = ei[i]; dst = ei[E + i]; } else { src = i - E; dst = i - E; }
      int t = spos[src];
      int r = (t >= s2) ? 2 : (t >= s1) ? 1 : 0;
      myb[k] = dst >> shiftB;
      mybin[k] = dst * 3 + r;
      myt[k] = t;
      atomicAdd(&lcnt[myb[k]], 1);
    }
  }
  __syncthreads();
  int c = lcnt[threadIdx.x];
  lbase[threadIdx.x] = (c > 0) ? atomicAdd(&bucketfill[threadIdx.x], c) : 0;
  __syncthreads();
  lcnt[threadIdx.x] = 0;          // reuse as per-bucket cursor
  __syncthreads();
  #pragma unroll
  for (int k = 0; k < 16; ++k) {
    if (myb[k] >= 0) {
      int slot = atomicAdd(&lcnt[myb[k]], 1);
      recs[lbase[myb[k]] + slot] = make_int2(mybin[k], myt[k]);
    }
  }
}

// stage 2: replay one bucket per WG; ssrc writes confined to the bucket's slice
__global__ __launch_bounds__(1024) void binscatter_kernel(
    const int2* __restrict__ recs, const int* __restrict__ off3,
    int* __restrict__ fill3, int* __restrict__ ssrc, int W, int N)
{
  int b = blockIdx.x;
  int d0 = min(b * W, N), d1 = min((b + 1) * W, N);
  int s = off3[d0 * 3], e = off3[d1 * 3];
  for (int i = s + threadIdx.x; i < e; i += 1024) {
    int2 rec = recs[i];
    int pz = atomicAdd(&fill3[rec.x], 1);
    ssrc[pz] = rec.y;
  }
}

__global__ __launch_bounds__(256) void permscatter_kernel(const int* __restrict__ role, int* __restrict__ rolefill,
                                                          int* __restrict__ spos, int* __restrict__ sposinv, int N)
{
  int i = blockIdx.x * 256 + threadIdx.x;
  int lane = threadIdx.x & 63;
  int r = (i < N) ? role[i] : -1;
  #pragma unroll
  for (int rr = 0; rr < 3; ++rr) {
    unsigned long long mask = __ballot(r == rr);
    if (!mask) continue;
    int base = 0;
    if (lane == 0) base = atomicAdd(&rolefill[rr], __popcll(mask));
    base = __shfl(base, 0);
    if (r == rr) {
      int rank = (int)__popcll(mask & ((1ull << lane) - 1ull));
      int pos = base + rank;
      spos[i] = pos;
      sposinv[pos] = i;
    }
  }
}

__global__ __launch_bounds__(256) void zeropad_kernel(const int* __restrict__ roleinfo,
                                                      bf16* __restrict__ Ax, bf16* __restrict__ Ah)
{
  int id = blockIdx.x * 256 + threadIdx.x;   // 98304
  int a = id / 49152, rem = id % 49152;
  int gp = rem / 16384, r2 = rem % 16384;
  int rr = r2 >> 6, c = r2 & 63;
  int gs = roleinfo[2 + gp * 2], gl = roleinfo[3 + gp * 2];
  if (rr < gl) {
    int row = gs + rr;
    size_t unit = (size_t)(row >> 4) * 1024 + c * 16 + (row & 15);
    bf16x8 z = {};
    ((bf16x8*)(a == 0 ? Ax : Ah))[unit] = z;
  }
}

// ---------------- prep ----------------
__global__ __launch_bounds__(256) void prep_xh_kernel(const float* __restrict__ x, const float* __restrict__ h,
                                                      const int* __restrict__ spos, u8* __restrict__ xq8,
                                                      bf16* __restrict__ Ax, bf16* __restrict__ Ah, int N)
{
  int g = blockIdx.x * 256 + threadIdx.x;
  if (g >= N * 32) return;
  int n = g >> 5, j = g & 31;
  int t = spos[n];
  const float* src = (j < 16) ? (x + (size_t)n * 128 + (j << 3))
                              : (h + (size_t)n * 128 + ((j - 16) << 3));
  float4 v0 = ((const float4*)src)[0];
  float4 v1 = ((const float4*)src)[1];
  int lo = __builtin_amdgcn_cvt_pk_fp8_f32(v0.x, v0.y, 0, false);
  lo = __builtin_amdgcn_cvt_pk_fp8_f32(v0.z, v0.w, lo, true);
  int hi = __builtin_amdgcn_cvt_pk_fp8_f32(v1.x, v1.y, 0, false);
  hi = __builtin_amdgcn_cvt_pk_fp8_f32(v1.z, v1.w, hi, true);
  *(int2*)(xq8 + (size_t)t * 256 + j * 8) = make_int2(lo, hi);
  bf16x8 o;
  o[0] = (bf16)v0.x; o[1] = (bf16)v0.y; o[2] = (bf16)v0.z; o[3] = (bf16)v0.w;
  o[4] = (bf16)v1.x; o[5] = (bf16)v1.y; o[6] = (bf16)v1.z; o[7] = (bf16)v1.w;
  size_t unit = (size_t)(t >> 4) * 1024 + (48 + (j & 15)) * 16 + (t & 15);
  ((bf16x8*)(j < 16 ? Ax : Ah))[unit] = o;
}

struct PrepW { const float* W[6]; const float* Wg[6]; const float* bg[6]; };
__global__ __launch_bounds__(256) void prep_wf_kernel(PrepW pw, bf16* __restrict__ Wf)
{
  int idx = blockIdx.x * 256 + threadIdx.x;
  if (idx >= 294912) return;
  int cv = idx / 49152, pos = idx % 49152;
  int ks4q = pos >> 10;
  int col = (pos >> 3) & 127, j = pos & 7;
  int k = (ks4q >> 2) * 32 + (ks4q & 3) * 8 + j;
  int r = k >> 7, kk = k & 127;
  float g = sigmoidf_(pw.Wg[cv][r * 128 + col] + pw.bg[cv][r * 128 + col]);
  Wf[idx] = (bf16)(pw.W[cv][kk * 128 + col] * g);
}

struct PrepP { const float* W[6]; const float* S[6]; };
__global__ __launch_bounds__(128) void prep_pf_kernel(PrepP pp, bf16* __restrict__ Pf)
{
  int b = blockIdx.x;                          // 6*3*128
  int cv = b / 384, rem = b % 384;
  int r = rem >> 7, kp = rem & 127;
  int col = threadIdx.x;
  const float* W = pp.W[cv] + (size_t)kp * 128;
  const float* S = pp.S[cv] + (size_t)r * 16384;
  float sum = 0.f;
  #pragma unroll 4
  for (int j2 = 0; j2 < 128; ++j2) sum += W[j2] * S[j2 * 128 + col];
  size_t o = (size_t)(cv * 3 + r) * 16384 + ((size_t)(kp >> 3) * 128 + col) * 8 + (kp & 7);
  Pf[o] = (bf16)sum;
}

// ---------------- gathers (t-ordered 8-node blocks, cooperative full-line NT writes) ----------------
#define ACCUM16(U, d) do { f32x2 f_;                                                   \
  f_ = __builtin_amdgcn_cvt_pk_f32_fp8((d).x, false); U[0]  += f_[0]; U[1]  += f_[1];  \
  f_ = __builtin_amdgcn_cvt_pk_f32_fp8((d).x, true);  U[2]  += f_[0]; U[3]  += f_[1];  \
  f_ = __builtin_amdgcn_cvt_pk_f32_fp8((d).y, false); U[4]  += f_[0]; U[5]  += f_[1];  \
  f_ = __builtin_amdgcn_cvt_pk_f32_fp8((d).y, true);  U[6]  += f_[0]; U[7]  += f_[1];  \
  f_ = __builtin_amdgcn_cvt_pk_f32_fp8((d).z, false); U[8]  += f_[0]; U[9]  += f_[1];  \
  f_ = __builtin_amdgcn_cvt_pk_f32_fp8((d).z, true);  U[10] += f_[0]; U[11] += f_[1];  \
  f_ = __builtin_amdgcn_cvt_pk_f32_fp8((d).w, false); U[12] += f_[0]; U[13] += f_[1];  \
  f_ = __builtin_amdgcn_cvt_pk_f32_fp8((d).w, true);  U[14] += f_[0]; U[15] += f_[1];  \
} while (0)

#define ACCSEL16(d, p) do {                      \
  if ((p) < o1)      { ACCUM16(u0, d); }         \
  else if ((p) < o2) { ACCUM16(u1, d); }         \
  else               { ACCUM16(u2, d); }         \
} while (0)

__global__ __launch_bounds__(512) void gather_xh_kernel(
    const u8* __restrict__ xq8, const int* __restrict__ off3, const int* __restrict__ ssrc,
    const int* __restrict__ sposinv, bf16* __restrict__ Ax, bf16* __restrict__ Ah,
    float4* __restrict__ cntf)
{
  __shared__ alignas(16) bf16 lds[8][768];
  int w = threadIdx.x >> 6, lane = threadIdx.x & 63;
  int t0 = blockIdx.x * 8;
  int t = t0 + w;
  int node = sposinv[t];                 // -1 for pad rows
  int qt = lane >> 4, ql = lane & 15;

  if (node >= 0) {
    int o0 = __builtin_amdgcn_readfirstlane(off3[node * 3]);
    int o1 = __builtin_amdgcn_readfirstlane(off3[node * 3 + 1]);
    int o2 = __builtin_amdgcn_readfirstlane(off3[node * 3 + 2]);
    int o3 = __builtin_amdgcn_readfirstlane(off3[node * 3 + 3]);
    float inv = 1.0f / (float)(o3 - o0);
    const u8* base = xq8 + ql * 16;

    float u0[16], u1[16], u2[16];
    #pragma unroll
    for (int k = 0; k < 16; ++k) { u0[k] = 0.f; u1[k] = 0.f; u2[k] = 0.f; }

    const int e = o3, emax = o3 - 1;
    for (int i = o0; i < e; i += 16) {
      int p0 = i + qt, p1 = p0 + 4, p2 = p0 + 8, p3 = p0 + 12;
      int t0i = ssrc[min(p0, emax)];
      int t1i = ssrc[min(p1, emax)];
      int t2i = ssrc[min(p2, emax)];
      int t3i = ssrc[min(p3, emax)];
      int4 d0 = make_int4(0, 0, 0, 0), d1 = d0, d2 = d0, d3 = d0;
      if (p0 < e) d0 = *(const int4*)(base + (size_t)t0i * 256);
      if (p1 < e) d1 = *(const int4*)(base + (size_t)t1i * 256);
      if (p2 < e) d2 = *(const int4*)(base + (size_t)t2i * 256);
      if (p3 < e) d3 = *(const int4*)(base + (size_t)t3i * 256);
      ACCSEL16(d0, p0);
      ACCSEL16(d1, p1);
      ACCSEL16(d2, p2);
      ACCSEL16(d3, p3);
    }

    #pragma unroll
    for (int k = 0; k < 16; ++k) {
      u0[k] += __shfl_xor(u0[k], 16); u0[k] += __shfl_xor(u0[k], 32);
      u1[k] += __shfl_xor(u1[k], 16); u1[k] += __shfl_xor(u1[k], 32);
      u2[k] += __shfl_xor(u2[k], 16); u2[k] += __shfl_xor(u2[k], 32);
    }
    if (qt == 0) {
      bf16x8 p0v, p1v;
      int sb0 = (ql < 8) ? (ql * 16) : (384 + (ql - 8) * 16);
      #pragma unroll
      for (int k = 0; k < 8; ++k) { p0v[k] = (bf16)(u0[k] * inv); p1v[k] = (bf16)(u0[8 + k] * inv); }
      *(bf16x8*)&lds[w][sb0] = p0v;
      *(bf16x8*)&lds[w][sb0 + 8] = p1v;
      #pragma unroll
      for (int k = 0; k < 8; ++k) { p0v[k] = (bf16)(u1[k] * inv); p1v[k] = (bf16)(u1[8 + k] * inv); }
      *(bf16x8*)&lds[w][sb0 + 128] = p0v;
      *(bf16x8*)&lds[w][sb0 + 136] = p1v;
      #pragma unroll
      for (int k = 0; k < 8; ++k) { p0v[k] = (bf16)(u2[k] * inv); p1v[k] = (bf16)(u2[8 + k] * inv); }
      *(bf16x8*)&lds[w][sb0 + 256] = p0v;
      *(bf16x8*)&lds[w][sb0 + 264] = p1v;
    }
    if (lane == 0)
      cntf[t] = make_float4((o1 - o0) * inv, (o2 - o1) * inv, (o3 - o2) * inv, (float)(o3 - o0));
  } else {
    // pad row: zero-fill this wave's LDS section so the cooperative write stores zeros
    if (lane < 48) {
      bf16x8 z = {};
      *(bf16x8*)&lds[w][lane * 16] = z;
      *(bf16x8*)&lds[w][lane * 16 + 8] = z;
    }
    if (lane == 0) cntf[t] = make_float4(0.f, 0.f, 0.f, 0.f);
  }

  __syncthreads();

  // cooperative write: 8 consecutive rows (t0..t0+7, same 16-group) -> full 128-B lines
  int tid = threadIdx.x;
  if (tid < 384) {
    int lc = tid >> 3, row = tid & 7;
    size_t unit = (size_t)(t0 >> 4) * 1024 + lc * 16 + (t0 & 15) + row;
    __builtin_nontemporal_store(*(const bf16x8*)&lds[row][lc * 8], (bf16x8*)Ax + unit);
    __builtin_nontemporal_store(*(const bf16x8*)&lds[row][384 + lc * 8], (bf16x8*)Ah + unit);
  }
}

#define ACCUM8(U, d) do { f32x2 f_;                                                  \
  f_ = __builtin_amdgcn_cvt_pk_f32_fp8((d).x, false); U[0] += f_[0]; U[1] += f_[1];  \
  f_ = __builtin_amdgcn_cvt_pk_f32_fp8((d).x, true);  U[2] += f_[0]; U[3] += f_[1];  \
  f_ = __builtin_amdgcn_cvt_pk_f32_fp8((d).y, false); U[4] += f_[0]; U[5] += f_[1];  \
  f_ = __builtin_amdgcn_cvt_pk_f32_fp8((d).y, true);  U[6] += f_[0]; U[7] += f_[1];  \
} while (0)

#define ACCSEL8(d, p) do {                      \
  if ((p) < o1)      { ACCUM8(v0, d); }         \
  else if ((p) < o2) { ACCUM8(v1, d); }         \
  else               { ACCUM8(v2, d); }         \
} while (0)

__global__ __launch_bounds__(512) void gather_q_kernel(
    const u8* __restrict__ q8, const int* __restrict__ off3, const int* __restrict__ ssrc,
    const int* __restrict__ sposinv, bf16* __restrict__ Aq)
{
  __shared__ alignas(16) bf16 lds[8][384];
  int w = threadIdx.x >> 6, lane = threadIdx.x & 63;
  int t0 = blockIdx.x * 8;
  int t = t0 + w;
  int node = sposinv[t];
  int qt = lane >> 4, ql = lane & 15;

  if (node >= 0) {
    int o0 = __builtin_amdgcn_readfirstlane(off3[node * 3]);
    int o1 = __builtin_amdgcn_readfirstlane(off3[node * 3 + 1]);
    int o2 = __builtin_amdgcn_readfirstlane(off3[node * 3 + 2]);
    int o3 = __builtin_amdgcn_readfirstlane(off3[node * 3 + 3]);
    float inv = 1.0f / (float)(o3 - o0);
    const u8* base = q8 + ql * 8;

    float v0[8], v1[8], v2[8];
    #pragma unroll
    for (int k = 0; k < 8; ++k) { v0[k] = 0.f; v1[k] = 0.f; v2[k] = 0.f; }

    const int e = o3, emax = o3 - 1;
    for (int i = o0; i < e; i += 16) {
      int p0 = i + qt, p1 = p0 + 4, p2 = p0 + 8, p3 = p0 + 12;
      int t0i = ssrc[min(p0, emax)];
      int t1i = ssrc[min(p1, emax)];
      int t2i = ssrc[min(p2, emax)];
      int t3i = ssrc[min(p3, emax)];
      int2 d0 = make_int2(0, 0), d1 = d0, d2 = d0, d3 = d0;
      if (p0 < e) d0 = *(const int2*)(base + (size_t)t0i * 128);
      if (p1 < e) d1 = *(const int2*)(base + (size_t)t1i * 128);
      if (p2 < e) d2 = *(const int2*)(base + (size_t)t2i * 128);
      if (p3 < e) d3 = *(const int2*)(base + (size_t)t3i * 128);
      ACCSEL8(d0, p0);
      ACCSEL8(d1, p1);
      ACCSEL8(d2, p2);
      ACCSEL8(d3, p3);
    }

    #pragma unroll
    for (int k = 0; k < 8; ++k) {
      v0[k] += __shfl_xor(v0[k], 16); v0[k] += __shfl_xor(v0[k], 32);
      v1[k] += __shfl_xor(v1[k], 16); v1[k] += __shfl_xor(v1[k], 32);
      v2[k] += __shfl_xor(v2[k], 16); v2[k] += __shfl_xor(v2[k], 32);
    }
    if (qt == 0) {
      bf16x8 pk;
      #pragma unroll
      for (int k = 0; k < 8; ++k) pk[k] = (bf16)(v0[k] * inv);
      *(bf16x8*)&lds[w][ql * 8] = pk;
      #pragma unroll
      for (int k = 0; k < 8; ++k) pk[k] = (bf16)(v1[k] * inv);
      *(bf16x8*)&lds[w][128 + ql * 8] = pk;
      #pragma unroll
      for (int k = 0; k < 8; ++k) pk[k] = (bf16)(v2[k] * inv);
      *(bf16x8*)&lds[w][256 + ql * 8] = pk;
    }
  } else {
    if (lane < 48) {
      bf16x8 z = {};
      *(bf16x8*)&lds[w][lane * 8] = z;
    }
  }

  __syncthreads();

  int tid = threadIdx.x;
  if (tid < 384) {
    int lc = tid >> 3, row = tid & 7;
    size_t unit = (size_t)(t0 >> 4) * 1024 + lc * 16 + (t0 & 15) + row;
    __builtin_nontemporal_store(*(const bf16x8*)&lds[row][lc * 8], (bf16x8*)Aq + unit);
  }
}

// ---------------- streaming MFMA GEMM (no LDS/barriers; 2 row-blocks per wave, 3 waves/SIMD) ----------------
struct GArgs {
  const bf16* Ap[5];
  const bf16* wf[5];
  const bf16* pf[5];
  bf16* out[5];
  const float* bias[5];
};

__global__ __launch_bounds__(256, 3) void gemm_kernel(GArgs ga, const float4* __restrict__ cntf,
                                                      const int* __restrict__ roleinfo)
{
  const int cv = blockIdx.y;
  const bf16* __restrict__ Ap = ga.Ap[cv];
  const bf16* __restrict__ wf = ga.wf[cv];
  const bf16* __restrict__ pf = ga.pf[cv];
  bf16* __restrict__ out = ga.out[cv];
  const float* __restrict__ bias = ga.bias[cv];

  const int w = threadIdx.x >> 6, lane = threadIdx.x & 63;
  const int q = lane >> 4, l = lane & 15;
  const int rb0 = blockIdx.x * 8 + w * 2;
  const int row0 = blockIdx.x * 128;
  const int s1 = roleinfo[0], s2 = roleinfo[1];
  const int role = (row0 >= s2) ? 2 : (row0 >= s1) ? 1 : 0;
  const int laneoff = q * 128 + l;

  f32x4 acc[2][8];
  #pragma unroll
  for (int j = 0; j < 2; ++j)
    #pragma unroll
    for (int ct = 0; ct < 8; ++ct)
      #pragma unroll
      for (int k = 0; k < 4; ++k) acc[j][ct][k] = 0.f;

  const bf16x8* A0 = (const bf16x8*)Ap + (size_t)rb0 * 1024 + lane;
  const bf16x8* WF = (const bf16x8*)wf + laneoff;
  const bf16x8* PF = (const bf16x8*)pf + role * 2048 + laneoff;

  #pragma unroll 2
  for (int ks = 0; ks < 16; ++ks) {
    const bf16x8* bp = (ks < 12) ? (WF + ks * 512) : (PF + (ks - 12) * 512);
    bf16x8 a0 = A0[ks * 64];
    bf16x8 a1 = A0[1024 + ks * 64];
    #pragma unroll
    for (int ct = 0; ct < 8; ++ct) {
      bf16x8 b = bp[ct * 16];
      acc[0][ct] = __builtin_amdgcn_mfma_f32_16x16x32_bf16(a0, b, acc[0][ct], 0, 0, 0);
      acc[1][ct] = __builtin_amdgcn_mfma_f32_16x16x32_bf16(a1, b, acc[1][ct], 0, 0, 0);
    }
  }

  const bool hb = (bias != nullptr);
  #pragma unroll
  for (int j = 0; j < 2; ++j) {
    int rb = rb0 + j;
    float4 cfs[4];
    if (hb) {
      #pragma unroll
      for (int reg = 0; reg < 4; ++reg) cfs[reg] = cntf[rb * 16 + q * 4 + reg];
    }
    #pragma unroll
    for (int ct = 0; ct < 8; ++ct) {
      int col = ct * 16 + l;
      float b0 = 0, b1 = 0, b2 = 0;
      if (hb) { b0 = bias[col]; b1 = bias[128 + col]; b2 = bias[256 + col]; }
      #pragma unroll
      for (int reg = 0; reg < 4; ++reg) {
        int t = rb * 16 + q * 4 + reg;
        float v = acc[j][ct][reg];
        if (hb) v += cfs[reg].x * b0 + cfs[reg].y * b1 + cfs[reg].z * b2;
        out[(size_t)t * 128 + col] = (bf16)fmaxf(v, 0.f);
      }
    }
  }
}

// ---------------- combines ----------------
__global__ __launch_bounds__(256) void combine1_kernel(
    const bf16* __restrict__ o0, const bf16* __restrict__ o1,
    const bf16* __restrict__ o2, const bf16* __restrict__ o3,
    const float* __restrict__ h, const int* __restrict__ spos,
    float* __restrict__ zbuf, u8* __restrict__ q8, bf16* __restrict__ Aq, int N)
{
  int g = blockIdx.x * 256 + threadIdx.x;
  if (g >= N * 16) return;
  int n = g >> 4, o = g & 15;
  int t = spos[n];
  size_t tb = (size_t)t * 16 + o;
  bf16x8 a0 = ((const bf16x8*)o0)[tb];
  bf16x8 a1 = ((const bf16x8*)o1)[tb];
  bf16x8 a2 = ((const bf16x8*)o2)[tb];
  bf16x8 a3 = ((const bf16x8*)o3)[tb];
  size_t nb = (size_t)n * 16 + o;
  float4 h0 = ((const float4*)h)[nb * 2];
  float4 h1 = ((const float4*)h)[nb * 2 + 1];
  float hv[8] = {h0.x, h0.y, h0.z, h0.w, h1.x, h1.y, h1.z, h1.w};
  float zv[8], qv[8];
  bf16x8 qb;
  #pragma unroll
  for (int j = 0; j < 8; ++j) {
    zv[j] = sigmoidf_((float)a0[j] + (float)a1[j]);
    qv[j] = sigmoidf_((float)a2[j] + (float)a3[j]) * hv[j];
    qb[j] = (bf16)qv[j];
  }
  ((float4*)zbuf)[nb * 2]     = make_float4(zv[0], zv[1], zv[2], zv[3]);
  ((float4*)zbuf)[nb * 2 + 1] = make_float4(zv[4], zv[5], zv[6], zv[7]);
  int lo = __builtin_amdgcn_cvt_pk_fp8_f32(qv[0], qv[1], 0, false);
  lo = __builtin_amdgcn_cvt_pk_fp8_f32(qv[2], qv[3], lo, true);
  int hi = __builtin_amdgcn_cvt_pk_fp8_f32(qv[4], qv[5], 0, false);
  hi = __builtin_amdgcn_cvt_pk_fp8_f32(qv[6], qv[7], hi, true);
  *(int2*)(q8 + (size_t)t * 128 + o * 8) = make_int2(lo, hi);
  size_t unit = (size_t)(t >> 4) * 1024 + (48 + o) * 16 + (t & 15);
  ((bf16x8*)Aq)[unit] = qb;
}

__global__ __launch_bounds__(256) void combine2_kernel(
    const float* __restrict__ zbuf, const bf16* __restrict__ o4, const bf16* __restrict__ o5,
    const float* __restrict__ h, const int* __restrict__ spos, float* __restrict__ out, int N)
{
  int g = blockIdx.x * 256 + threadIdx.x;
  if (g >= N * 16) return;
  int n = g >> 4, o = g & 15;
  int t = spos[n];
  size_t tb = (size_t)t * 16 + o;
  bf16x8 a = ((const bf16x8*)o4)[tb];
  bf16x8 b = ((const bf16x8*)o5)[tb];
  size_t nb = (size_t)n * 16 + o;
  float4 z0 = ((const float4*)zbuf)[nb * 2];
  float4 z1 = ((const float4*)zbuf)[nb * 2 + 1];
  float4 h0 = ((const float4*)h)[nb * 2];
  float4 h1 = ((const float4*)h)[nb * 2 + 1];
  float zv[8] = {z0.x, z0.y, z0.z, z0.w, z1.x, z1.y, z1.z, z1.w};
  float hv[8] = {h0.x, h0.y, h0.z, h0.w, h1.x, h1.y, h1.z, h1.w};
  float ov[8];
  #pragma unroll
  for (int j = 0; j < 8; ++j)
    ov[j] = zv[j] * hv[j] + (1.f - zv[j]) * tanhf((float)a[j] + (float)b[j]);
  ((float4*)out)[nb * 2]     = make_float4(ov[0], ov[1], ov[2], ov[3]);
  ((float4*)out)[nb * 2 + 1] = make_float4(ov[4], ov[5], ov[6], ov[7]);
}

// ---------------- host ----------------
extern "C" void kernel_launch(void* const* d_in, const int* in_sizes, int n_in,
                              void* d_out, int out_size, void* d_ws, size_t ws_size,
                              hipStream_t stream)
{
  (void)n_in; (void)out_size; (void)ws_size;
  const float* x    = (const float*)d_in[0];
  const float* h    = (const float*)d_in[1];
  const int*   ei   = (const int*)d_in[2];
  const int*   role = (const int*)d_in[3];
  const int N = in_sizes[0] / DH;
  const int E = in_sizes[2] / 2;
  const int Etot = E + N;
  const int rows_pad = ((N + 765) + 255) & ~255;
  const int gx = rows_pad / 128;
  const int n3 = N * 3;
  const int nb3 = (n3 + 1023) / 1024;

  // bucket geometry: <=256 buckets of W=2^shiftB dst rows
  int shiftB = 8;
  while (((N - 1) >> shiftB) >= 256) ++shiftB;
  const int W = 1 << shiftB;
  const int NB = (N + W - 1) >> shiftB;

  // conv order: 0 xz, 1 hz, 2 xr, 3 hr, 4 xh, 5 hh
  static const int Wi[6]  = {4, 9, 13, 18, 22, 27};
  static const int Wgi[6] = {5, 10, 14, 19, 23, 28};
  static const int bgi[6] = {6, 11, 15, 20, 24, 29};
  static const int Si[6]  = {7, 12, 16, 21, 25, 30};

  char* p = (char*)d_ws;
  auto alloc = [&](size_t bytes) -> char* {
    char* r = p;
    p += (bytes + 255) & ~(size_t)255;
    return r;
  };

  bf16* Ax = (bf16*)alloc((size_t)rows_pad * 512 * 2);   // Aq aliases Ax
  bf16* Ah = (bf16*)alloc((size_t)rows_pad * 512 * 2);
  bf16* Aq = Ax;
  u8* xq8  = (u8*)alloc((size_t)rows_pad * 256);
  u8* q8   = (u8*)alloc((size_t)rows_pad * 128);
  bf16* outs[6];
  for (int c = 0; c < 5; ++c) outs[c] = (bf16*)alloc((size_t)rows_pad * 128 * 2);
  outs[5] = outs[0];
  float* zbuf = (float*)alloc((size_t)N * 128 * 4);
  float4* cntf = (float4*)alloc((size_t)rows_pad * 16);
  bf16* Wf = (bf16*)alloc((size_t)6 * 49152 * 2);
  bf16* Pf = (bf16*)alloc((size_t)18 * 16384 * 2);
  int* cnt3  = (int*)alloc((size_t)n3 * 4);
  int* off3  = (int*)alloc((size_t)(n3 + 1) * 4);
  int* fill3 = (int*)alloc((size_t)n3 * 4);
  int* bsum  = (int*)alloc((size_t)(nb3 + 1) * 4);
  int* ssrc  = (int*)alloc((size_t)Etot * 4);
  int2* recs = (int2*)alloc((size_t)Etot * 8);
  int* spos  = (int*)alloc((size_t)N * 4);
  int* sposinv = (int*)alloc((size_t)rows_pad * 4);
  int* rolecnt  = (int*)alloc(64);
  int* rolefill = (int*)alloc(64);
  int* roleinfo = (int*)alloc(64);
  int* bucketfill = (int*)alloc((size_t)(NB + 1) * 4);

  hipMemsetAsync(cnt3, 0, (size_t)n3 * 4, stream);
  hipMemsetAsync(rolecnt, 0, 16, stream);
  hipMemsetAsync(sposinv, 0xFF, (size_t)rows_pad * 4, stream);   // -1 = pad row

  int egrid = (Etot + 255) / 256;
  int ngrid = (N + 255) / 256;
  hist_kernel<<<egrid, 256, 0, stream>>>(ei, role, cnt3, rolecnt, E, N);
  scan1_kernel<<<nb3, 1024, 0, stream>>>(cnt3, off3, bsum, n3);
  scan2_kernel<<<1, 64, 0, stream>>>(bsum, nb3, rolecnt, rolefill, roleinfo);
  scan3_kernel<<<nb3, 1024, 0, stream>>>(off3, fill3, bsum, n3);
  permscatter_kernel<<<ngrid, 256, 0, stream>>>(role, rolefill, spos, sposinv, N);
  bucketinit_kernel<<<1, 256, 0, stream>>>(off3, bucketfill, NB, W, N);
  partition_kernel<<<(Etot + 4095) / 4096, 256, 0, stream>>>(ei, spos, roleinfo, bucketfill,
                                                             recs, E, N, shiftB);
  binscatter_kernel<<<NB, 1024, 0, stream>>>(recs, off3, fill3, ssrc, W, N);
  zeropad_kernel<<<384, 256, 0, stream>>>(roleinfo, Ax, Ah);

  prep_xh_kernel<<<(N * 32 + 255) / 256, 256, 0, stream>>>(x, h, spos, xq8, Ax, Ah, N);

  PrepW pw;
  for (int c = 0; c < 6; ++c) {
    pw.W[c] = (const float*)d_in[Wi[c]];
    pw.Wg[c] = (const float*)d_in[Wgi[c]];
    pw.bg[c] = (const float*)d_in[bgi[c]];
  }
  prep_wf_kernel<<<1152, 256, 0, stream>>>(pw, Wf);
  PrepP pp;
  for (int c = 0; c < 6; ++c) { pp.W[c] = (const float*)d_in[Wi[c]]; pp.S[c] = (const float*)d_in[Si[c]]; }
  prep_pf_kernel<<<2304, 128, 0, stream>>>(pp, Pf);

  gather_xh_kernel<<<rows_pad / 8, 512, 0, stream>>>(xq8, off3, ssrc, sposinv, Ax, Ah, cntf);

  // pass 1: one dispatch, cv 0..4 = {xz,xr,xh on Ax (bias)} + {hz,hr on Ah}
  GArgs g0;
  { int cvs[5] = {0, 2, 4, 1, 3};
    static const int bi2[5] = {8, 17, 26, -1, -1};
    const bf16* Apts[5] = {Ax, Ax, Ax, Ah, Ah};
    for (int k = 0; k < 5; ++k) {
      int c = cvs[k];
      g0.Ap[k] = Apts[k];
      g0.wf[k] = Wf + (size_t)c * 49152;
      g0.pf[k] = Pf + (size_t)c * 3 * 16384;
      g0.out[k] = outs[c];
      g0.bias[k] = (bi2[k] >= 0) ? (const float*)d_in[bi2[k]] : nullptr;
    } }
  gemm_kernel<<<dim3(gx, 5), 256, 0, stream>>>(g0, cntf, roleinfo);

  combine1_kernel<<<(N * 16 + 255) / 256, 256, 0, stream>>>(outs[0], outs[1], outs[2], outs[3],
                                                            h, spos, zbuf, q8, Aq, N);

  gather_q_kernel<<<rows_pad / 8, 512, 0, stream>>>(q8, off3, ssrc, sposinv, Aq);

  // pass 2: conv hh(5) on Aq
  GArgs g2 = {};
  g2.Ap[0] = Aq;
  g2.wf[0] = Wf + (size_t)5 * 49152;
  g2.pf[0] = Pf + (size_t)5 * 3 * 16384;
  g2.out[0] = outs[5];
  g2.bias[0] = nullptr;
  gemm_kernel<<<dim3(gx, 1), 256, 0, stream>>>(g2, cntf, roleinfo);

  combine2_kernel<<<(N * 16 + 255) / 256, 256, 0, stream>>>(zbuf, outs[4], outs[5], h, spos,
                                                            (float*)d_out, N);
}